// Round 6
// baseline (352.592 us; speedup 1.0000x reference)
//
#include <hip/hip_runtime.h>
#include <hip/hip_bf16.h>

// B=4, N=256, F=64, H=256, A=16, T=3.  BN=1024 rows.
// bf16 inputs (runtime-verified); adjacency int32.
// GEMMs: bf16 MFMA 16x16x32. Weights are EXACT in bf16 (inputs are bf16).
// Precision: activations h/Ehat stored as split hi/lo bf16 pairs along K,
// weights duplicated along K -> A_hi@B + A_lo@B in one MFMA GEMM (~fp32 acc).
// R1: agg.gi fused via precomputed Wg = W2hat.Wih (3-term split-K, K=864).
// R2: wg_kernel latency fix. 311us.
// R3/R4: megakernel arc abandoned (grid barrier >= 25us: L2 wb/inv per phase).
// R5: intra-kernel fusion (convwg, prenet, gigru) -> 337us. Fusions kept but
//     prenet(16 blk)/gigru(64 blk) under-parallelized.
// R6: (1) prenet 32 blocks, gigru 128 blocks (8 col-groups) - bitwise same;
//     (2) detect merged into convwg (redundant per-block scan), convert x2;
//     (3) readout merged into last gigru via per-graph arrival counters
//         (threadfence + device atomicAdd; 32nd block does the readout).
//     13 -> 11 dispatches.

typedef unsigned short ushort_t;
typedef short bf8_t __attribute__((ext_vector_type(8)));
typedef float f4_t  __attribute__((ext_vector_type(4)));

#define BN_ROWS 1024

// ---- bf16 regions (USHORT offsets) ----
#define UB_NFB    0         // 65536   NF [1024][64] (exact)
#define UB_PW1T   65536     // 16384   preW1^T [256][64]
#define UB_PW2T   81920     // 65536   preW2^T [256][256]
#define UB_WCATT  147456    // 655360  Wcat^T dup [1280][512]
#define UB_WGT    802816    // 663552  Wg^T [768][864] = [hi(288)|hi(288)|lo(288)]
#define UB_H2     1728512   // 524288  h  [1024][512] hi|lo
#define UB_EHAT2  2252800   // 884736  Ehat [1024][864] hi(288)|lo(288)|hi(288)

// ---- fp32 regions (FLOAT offsets) ----
#define F_PREB1   1568768   // 256
#define F_PREB2   1569024   // 256
#define F_BCAT    1569280   // 1280  [msg_b1 | 0 | gru_bhh]
#define F_BIH     1570560   // 768
#define F_ROW1    1571328   // 65536
#define F_ROB1    1636864   // 256
#define F_ROW2    1637120   // 4096
#define F_ROB2    1641216   // 16
#define F_H       1641232   // 262144
#define F_HCAT    1903376   // 1310720 [hi_p | hj | gh]
#define F_FLAG    4000528   // 1 int
#define F_GCNT    4000532   // 4 ints: per-graph readout arrival counters

// ---- convert index space ----
#define CVa 65536     // end NFB
#define CVb 81920     // end PW1T
#define CVc 147456    // end PW2T
#define CVd 802816    // end WCATT
#define CV_TOTAL 875280   // + 72464 fp32 tail
#define NCONV 1710        // convert blocks (2 elems/thread); wg blocks follow

__device__ __forceinline__ float bf2f(ushort_t u) {
    return __uint_as_float(((unsigned int)u) << 16);
}
__device__ __forceinline__ ushort_t f2b(float v) {
    __hip_bfloat16 b = __float2bfloat16(v);
    return *reinterpret_cast<ushort_t*>(&b);
}
__device__ __forceinline__ float relu(float v) { return v < 0.f ? 0.f : v; }  // NaN-propagating
__device__ __forceinline__ float ld(const void* p, int i, int isf32) {
    return isf32 ? ((const float*)p)[i] : bf2f(((const ushort_t*)p)[i]);
}

// detect + convert (blocks [0,NCONV)) + wg (blocks [NCONV,NCONV+216)).
__global__ __launch_bounds__(256) void convwg_kernel(
    const void* nf, const void* preW1, const void* preb1, const void* preW2, const void* preb2,
    const void* msgW1, const void* msgb1, const void* msgW2, const void* msgb2,
    const void* gruWih, const void* gruWhh, const void* grubih, const void* grubhh,
    const void* roW1, const void* rob1, const void* roW2, const void* rob2,
    float* __restrict__ w)
{
    __shared__ float w2s[4 * 256];
    __shared__ int cnt;
    const int t = threadIdx.x;
    ushort_t* wb = (ushort_t*)w;

    // ---- inline detect (redundant per block; 4KB L2-hit scan) ----
    if (t == 0) cnt = 0;
    __syncthreads();
    {
        const ushort_t* nf0 = (const ushort_t*)nf;
        int bad = 0;
        for (int i = 0; i < 8; ++i) {
            ushort_t u = nf0[(t * 8 + i) * 2];
            int ex = (u >> 7) & 0xFF;
            if ((u & 0x7fff) != 0 && (ex < 100 || ex > 140)) bad++;
        }
        atomicAdd(&cnt, bad);
    }
    __syncthreads();
    const int f32 = (cnt > 512) ? 1 : 0;

    if (blockIdx.x == 0) {          // publish flag + zero readout counters
        if (t < 4) ((int*)(w + F_GCNT))[t] = 0;
        if (t == 4) *(int*)(w + F_FLAG) = f32;
    }

    if (blockIdx.x < NCONV) {
        const int e0 = (blockIdx.x * 256 + t) * 2;
#pragma unroll
        for (int u2 = 0; u2 < 2; ++u2) {
            int e = e0 + u2;
            if (e >= CV_TOTAL) break;
            if (e < CVa) {                                    // NF
                wb[UB_NFB + e] = f2b(ld(nf, e, f32));
            } else if (e < CVb) {                             // preW1^T [256][64]
                int i = e - CVa; int n = i >> 6, k = i & 63;
                wb[UB_PW1T + i] = f2b(ld(preW1, k * 256 + n, f32));
            } else if (e < CVc) {                             // preW2^T [256][256]
                int i = e - CVb; int n = i >> 8, k = i & 255;
                wb[UB_PW2T + i] = f2b(ld(preW2, k * 256 + n, f32));
            } else if (e < CVd) {                             // Wcat^T dup [1280][512]
                int i = e - CVc; int n = i >> 9, k = (i & 511) & 255;
                float v;
                if (n < 256)      v = ld(msgW1, k * 256 + n, f32);
                else if (n < 512) v = ld(msgW1, (256 + k) * 256 + (n - 256), f32);
                else              v = ld(gruWhh, k * 768 + (n - 512), f32);
                wb[UB_WCATT + i] = f2b(v);
            } else {                                          // fp32 tail
                int f = e - CVd;
                float v;
                if (f < 256)        v = ld(preb1, f, f32);
                else if (f < 512)   v = ld(preb2, f - 256, f32);
                else if (f < 1792) {
                    int c = f - 512;
                    if (c < 256)      v = ld(msgb1, c, f32);
                    else if (c < 512) v = 0.f;
                    else              v = ld(grubhh, c - 512, f32);
                }
                else if (f < 2560)  v = ld(grubih, f - 1792, f32);
                else if (f < 68096) v = ld(roW1, f - 2560, f32);
                else if (f < 68352) v = ld(rob1, f - 68096, f32);
                else if (f < 72448) v = ld(roW2, f - 68352, f32);
                else                v = ld(rob2, f - 72448, f32);
                w[F_PREB1 + f] = v;
            }
        }
        return;
    }

    // ---- wg path: Wg[k][p] = sum_n W2hat[k][n]*Wih[n][p] -> WgT[p][864] ----
    const int wt = blockIdx.x - NCONV;   // [0,216)
    const int p0 = (wt % 3) * 256;
    const int k0 = (wt / 3) * 4;
    for (int i = t; i < 4 * 256; i += 256) {
        int r = i >> 8, n = i & 255;
        int krow = k0 + r;
        float v;
        if (krow < 256)       v = ld(msgW2, krow * 256 + n, f32);
        else if (krow == 256) v = ld(msgb2, n, f32);
        else                  v = 0.f;
        w2s[i] = v;
    }
    __syncthreads();
    const int p = p0 + t;
    float acc4[4] = {};
    for (int n0 = 0; n0 < 256; n0 += 32) {
        float wv[32];
#pragma unroll
        for (int i = 0; i < 32; ++i)
            wv[i] = ld(gruWih, (n0 + i) * 768 + p, f32);
#pragma unroll
        for (int r = 0; r < 4; ++r) {
            float acc = acc4[r];
#pragma unroll
            for (int q = 0; q < 8; ++q) {
                f4_t w4 = *(const f4_t*)&w2s[r * 256 + n0 + q * 4];
                acc += w4[0] * wv[q * 4 + 0] + w4[1] * wv[q * 4 + 1]
                     + w4[2] * wv[q * 4 + 2] + w4[3] * wv[q * 4 + 3];
            }
            acc4[r] = acc;
        }
    }
#pragma unroll
    for (int r = 0; r < 4; ++r) {
        int krow = k0 + r;
        ushort_t hi = f2b(acc4[r]);
        ushort_t lo = f2b(acc4[r] - bf2f(hi));
        wb[UB_WGT + p * 864 + krow] = hi;
        wb[UB_WGT + p * 864 + 288 + krow] = hi;
        wb[UB_WGT + p * 864 + 576 + krow] = lo;
    }
}

// Fused pre-net: X = relu(NF@preW1+b1) (in LDS), h = X@preW2+b2.
// 32 blocks x 32 rows; wave w: rows (w&1)*16, cols (w>>1)*128 (8 n-frags).
__global__ __launch_bounds__(256) void prenet_kernel(float* __restrict__ w)
{
    __shared__ ushort_t As[32 * 64];    // NF tile      4KB
    __shared__ ushort_t Xs[32 * 256];   // X tile      16KB
    __shared__ ushort_t Bs[256 * 32];   // weight slab 16KB
    ushort_t* wb = (ushort_t*)w;
    const int t = threadIdx.x;
    const int wave = t >> 6, lane = t & 63;
    const int ln = lane & 15, quad = lane >> 4;
    const int wr = (wave & 1) * 16, wc = (wave >> 1) * 128;
    const int rbase = blockIdx.x * 32;
    const int srow = t >> 2, skc = (t & 3) << 3;

    // stage NF tile [32][64]: 1 bf8 per thread
    {
        int row = t >> 3, kc = (t & 7) << 3;
        *(bf8_t*)(&As[row * 64 + kc]) =
            *(const bf8_t*)(&wb[UB_NFB + (rbase + row) * 64 + kc]);
    }

    f4_t acc[8] = {};
    // phase A: X = relu(NF @ PW1T + b1), K=64
    for (int k0 = 0; k0 < 64; k0 += 32) {
        __syncthreads();
#pragma unroll
        for (int rr = 0; rr < 4; ++rr) {
            int n = srow + 64 * rr;
            *(bf8_t*)(&Bs[n * 32 + skc]) =
                *(const bf8_t*)(&wb[UB_PW1T + n * 64 + k0 + skc]);
        }
        __syncthreads();
        bf8_t af = *(const bf8_t*)(&As[(wr + ln) * 64 + k0 + quad * 8]);
#pragma unroll
        for (int n = 0; n < 8; ++n) {
            bf8_t bfr = *(const bf8_t*)(&Bs[(wc + n * 16 + ln) * 32 + quad * 8]);
            acc[n] = __builtin_amdgcn_mfma_f32_16x16x32_bf16(af, bfr, acc[n], 0, 0, 0);
        }
    }
    __syncthreads();
#pragma unroll
    for (int n = 0; n < 8; ++n) {
        int col = wc + n * 16 + ln;
        float bb = w[F_PREB1 + col];
#pragma unroll
        for (int r = 0; r < 4; ++r) {
            int row = wr + quad * 4 + r;
            Xs[row * 256 + col] = f2b(relu(acc[n][r] + bb));
        }
        acc[n] = (f4_t){0.f, 0.f, 0.f, 0.f};
    }
    __syncthreads();

    // phase B: h = X @ PW2T + b2, K=256
    for (int k0 = 0; k0 < 256; k0 += 32) {
        __syncthreads();
#pragma unroll
        for (int rr = 0; rr < 4; ++rr) {
            int n = srow + 64 * rr;
            *(bf8_t*)(&Bs[n * 32 + skc]) =
                *(const bf8_t*)(&wb[UB_PW2T + n * 256 + k0 + skc]);
        }
        __syncthreads();
        bf8_t af = *(const bf8_t*)(&Xs[(wr + ln) * 256 + k0 + quad * 8]);
#pragma unroll
        for (int n = 0; n < 8; ++n) {
            bf8_t bfr = *(const bf8_t*)(&Bs[(wc + n * 16 + ln) * 32 + quad * 8]);
            acc[n] = __builtin_amdgcn_mfma_f32_16x16x32_bf16(af, bfr, acc[n], 0, 0, 0);
        }
    }
#pragma unroll
    for (int n = 0; n < 8; ++n) {
        int col = wc + n * 16 + ln;
        float bb = w[F_PREB2 + col];
#pragma unroll
        for (int r = 0; r < 4; ++r) {
            int grow = rbase + wr + quad * 4 + r;
            float v = acc[n][r] + bb;
            w[F_H + grow * 256 + col] = v;
            ushort_t hi = f2b(v);
            wb[UB_H2 + grow * 512 + col] = hi;
            wb[UB_H2 + grow * 512 + 256 + col] = f2b(v - bf2f(hi));
        }
    }
}

// bf16 MFMA GEMM: C[M,N] = A[M,K] @ Bt[N,K]^T + bias.  64x128 tiles. (hcat)
__global__ __launch_bounds__(256) void mgemm_k(
    const ushort_t* __restrict__ A,
    const ushort_t* __restrict__ Bt,
    const float* __restrict__ bias,
    float* __restrict__ C,
    int K, int N)
{
    __shared__ ushort_t As[64 * 32];
    __shared__ ushort_t Bs[128 * 32];
    const int t = threadIdx.x;
    const int wave = t >> 6, lane = t & 63;
    const int ln = lane & 15, quad = lane >> 4;
    const int bm = blockIdx.y * 64, bn = blockIdx.x * 128;
    const int wm = (wave >> 1) * 32, wn = (wave & 1) * 64;
    const int srow = t >> 2, skc = (t & 3) << 3;

    f4_t acc[2][4] = {};

    for (int k0 = 0; k0 < K; k0 += 32) {
        __syncthreads();
        *(bf8_t*)(&As[srow * 32 + skc]) = *(const bf8_t*)(&A[(bm + srow) * K + k0 + skc]);
#pragma unroll
        for (int r = 0; r < 2; ++r) {
            int row = srow + r * 64;
            *(bf8_t*)(&Bs[row * 32 + skc]) = *(const bf8_t*)(&Bt[(bn + row) * K + k0 + skc]);
        }
        __syncthreads();
        bf8_t af[2], bfr[4];
#pragma unroll
        for (int i = 0; i < 2; ++i)
            af[i]  = *(const bf8_t*)(&As[(wm + i * 16 + ln) * 32 + quad * 8]);
#pragma unroll
        for (int i = 0; i < 4; ++i)
            bfr[i] = *(const bf8_t*)(&Bs[(wn + i * 16 + ln) * 32 + quad * 8]);
#pragma unroll
        for (int mi = 0; mi < 2; ++mi)
#pragma unroll
            for (int ni = 0; ni < 4; ++ni)
                acc[mi][ni] = __builtin_amdgcn_mfma_f32_16x16x32_bf16(
                    af[mi], bfr[ni], acc[mi][ni], 0, 0, 0);
    }

#pragma unroll
    for (int mi = 0; mi < 2; ++mi) {
#pragma unroll
        for (int ni = 0; ni < 4; ++ni) {
            int col = bn + wn + ni * 16 + ln;
            float bb = bias[col];
#pragma unroll
            for (int r = 0; r < 4; ++r) {
                int row = bm + wm + mi * 16 + quad * 4 + r;
                C[row * N + col] = acc[mi][ni][r] + bb;
            }
        }
    }
}

// Ehat[row] (width 864): [ sum relu(hi_p+hj) hi | deg | 0 | lo | 0 | hi | deg | 0 ]
__global__ __launch_bounds__(256) void msg_kernel(
    const float* __restrict__ hcat,   // [1024][1280]: [hi_p | hj | gh]
    const int*   __restrict__ adj,    // [1024][256]
    ushort_t* __restrict__ ehat)      // [1024][864]
{
    const int row = blockIdx.x;
    const int t = threadIdx.x;
    __shared__ int ej[256];
    __shared__ int ecnt;
    if (t == 0) ecnt = 0;
    __syncthreads();
    if (adj[row * 256 + t]) { int p = atomicAdd(&ecnt, 1); ej[p] = t; }
    const float hi = hcat[row * 1280 + t];
    const float* hjb = hcat + (row >> 8) * 256 * 1280 + 256;
    __syncthreads();
    const int ne = ecnt;
    float acc = 0.f;
#pragma unroll 4
    for (int p = 0; p < ne; ++p) {
        int j = ej[p];
        acc += relu(hi + hjb[j * 1280 + t]);
    }
    ushort_t h16 = f2b(acc);
    ushort_t l16 = f2b(acc - bf2f(h16));
    ushort_t* er = ehat + row * 864;
    er[t] = h16;
    er[288 + t] = l16;
    er[576 + t] = h16;
    if (t < 32) {
        ushort_t d = f2b(t == 0 ? (float)ne : 0.f);  // deg exact (<=256)
        er[256 + t] = d;
        er[544 + t] = 0;
        er[832 + t] = d;
    }
}

// Fused gi-GEMM + GRU.  128 blocks = 16 rowgroups x 8 colgroups (32 cols/gate).
// gi = Ehat @ Wg + bih (K=864); GRU in epilogue from registers.
// FINAL: last block of each graph (per-graph arrival counter) does readout.
template<int FINAL>
__global__ __launch_bounds__(256) void gigru_kernel(float* __restrict__ w,
                                                    void* __restrict__ out)
{
    __shared__ ushort_t As[64 * 32];    // 4KB
    __shared__ ushort_t Bs[96 * 32];    // 6KB
    __shared__ float gl[256];
    __shared__ float t1[256];
    __shared__ int donef;
    ushort_t* wb = (ushort_t*)w;
    const int t = threadIdx.x;
    const int wave = t >> 6, lane = t & 63;
    const int ln = lane & 15, quad = lane >> 4;
    const int rg = blockIdx.x >> 3, cg = blockIdx.x & 7;
    const int rbase = rg * 64;
    const int srow = t >> 2, skc = (t & 3) << 3;

    f4_t acc[6] = {};

    for (int k0 = 0; k0 < 864; k0 += 32) {
        __syncthreads();
        *(bf8_t*)(&As[srow * 32 + skc]) =
            *(const bf8_t*)(&wb[UB_EHAT2 + (rbase + srow) * 864 + k0 + skc]);
#pragma unroll
        for (int rr = 0; rr < 2; ++rr) {
            int br = srow + 64 * rr;                       // [0,96)
            if (br < 96) {
                int wrow = (br >> 5) * 256 + cg * 32 + (br & 31);
                *(bf8_t*)(&Bs[br * 32 + skc]) =
                    *(const bf8_t*)(&wb[UB_WGT + wrow * 864 + k0 + skc]);
            }
        }
        __syncthreads();
        bf8_t af = *(const bf8_t*)(&As[(wave * 16 + ln) * 32 + quad * 8]);
#pragma unroll
        for (int n = 0; n < 6; ++n) {
            bf8_t bfr = *(const bf8_t*)(&Bs[(n * 16 + ln) * 32 + quad * 8]);
            acc[n] = __builtin_amdgcn_mfma_f32_16x16x32_bf16(af, bfr, acc[n], 0, 0, 0);
        }
    }

    // GRU epilogue: n 0..1 = ir frags, 2..3 = iz, 4..5 = in (same col pair).
#pragma unroll
    for (int n = 0; n < 2; ++n) {
        int col = cg * 32 + n * 16 + ln;
        float bi_r = w[F_BIH + col];
        float bi_z = w[F_BIH + 256 + col];
        float bi_n = w[F_BIH + 512 + col];
#pragma unroll
        for (int r = 0; r < 4; ++r) {
            int row = rbase + wave * 16 + quad * 4 + r;
            float ir = acc[n][r] + bi_r;
            float iz = acc[n + 2][r] + bi_z;
            float in = acc[n + 4][r] + bi_n;
            const float* ghr = w + F_HCAT + row * 1280 + 512;
            float hr = ghr[col], hz = ghr[256 + col], hn = ghr[512 + col];
            float rg_ = 1.f / (1.f + __expf(-(ir + hr)));
            float z   = 1.f / (1.f + __expf(-(iz + hz)));
            float nn  = tanhf(in + rg_ * hn);
            float ho = w[F_H + row * 256 + col];
            float hv = (1.f - z) * nn + z * ho;
            w[F_H + row * 256 + col] = hv;
            if (!FINAL) {
                ushort_t hb = f2b(hv);
                wb[UB_H2 + row * 512 + col] = hb;
                wb[UB_H2 + row * 512 + 256 + col] = f2b(hv - bf2f(hb));
            }
        }
    }

    if (FINAL) {
        // per-graph arrival counter: 32 blocks/graph; last one does readout.
        const int g = blockIdx.x >> 5;
        __syncthreads();
        if (t == 0) {
            __threadfence();                           // release h writes
            int prev = atomicAdd((int*)(w + F_GCNT) + g, 1);
            donef = (prev == 31);
        }
        __syncthreads();
        if (!donef) return;
        __threadfence();                               // acquire others' h

        const float* hb = w + F_H + g * 256 * 256;
        float s = 0.f;
        for (int n = 0; n < 256; ++n) s += hb[n * 256 + t];
        gl[t] = s;
        __syncthreads();
        float acc1 = w[F_ROB1 + t];
        for (int k = 0; k < 256; ++k) acc1 += gl[k] * w[F_ROW1 + k * 256 + t];
        t1[t] = relu(acc1);
        __syncthreads();
        if (t < 16) {
            float q = w[F_ROB2 + t];
            for (int k = 0; k < 256; ++k) q += t1[k] * w[F_ROW2 + k * 16 + t];
            if (*(const int*)(w + F_FLAG)) ((float*)out)[g * 16 + t] = q;
            else ((__hip_bfloat16*)out)[g * 16 + t] = __float2bfloat16(q);
        }
    }
}

extern "C" void kernel_launch(void* const* d_in, const int* in_sizes, int n_in,
                              void* d_out, int out_size, void* d_ws, size_t ws_size,
                              hipStream_t stream) {
    float* w = (float*)d_ws;
    ushort_t* wb = (ushort_t*)d_ws;

    static const int dictSz[18]  = {65536,262144,16384,256,65536,256,131072,256,65536,256,
                                    196608,196608,768,768,65536,256,4096,16};
    static const int alphaSz[18] = {262144,196608,196608,768,768,131072,65536,256,256,
                                    65536,16384,65536,256,256,65536,4096,256,16};
    static const int alphaPos[18] = {9,0,10,12,11,13,5,7,6,8,2,1,4,3,14,16,15,17};
    bool dictOK = true, alphaOK = true;
    for (int i = 0; i < 18 && i < n_in; ++i) {
        if (in_sizes[i] != dictSz[i])  dictOK = false;
        if (in_sizes[i] != alphaSz[i]) alphaOK = false;
    }
    const void* P[18];
    for (int l = 0; l < 18; ++l) P[l] = d_in[(!dictOK && alphaOK) ? alphaPos[l] : l];
    const int* adj = (const int*)P[1];

    convwg_kernel<<<NCONV + 216, 256, 0, stream>>>(
        P[0], P[2], P[3], P[4], P[5], P[6], P[7], P[8], P[9],
        P[10], P[11], P[12], P[13], P[14], P[15], P[16], P[17], w);

    prenet_kernel<<<32, 256, 0, stream>>>(w);

    for (int it = 0; it < 3; ++it) {
        // hcat = h @ [W1_i|W1_j|Whh] + [b1|0|bhh]   (A = h hi|lo, K=512)
        mgemm_k<<<dim3(10, 16), 256, 0, stream>>>(
            wb + UB_H2, wb + UB_WCATT, w + F_BCAT, w + F_HCAT, 512, 1280);
        msg_kernel<<<BN_ROWS, 256, 0, stream>>>(w + F_HCAT, adj, wb + UB_EHAT2);
        if (it < 2)
            gigru_kernel<0><<<128, 256, 0, stream>>>(w, d_out);
        else
            gigru_kernel<1><<<128, 256, 0, stream>>>(w, d_out);
    }
}

// Round 7
// 308.895 us; speedup vs baseline: 1.1415x; 1.1415x over previous
//
#include <hip/hip_runtime.h>
#include <hip/hip_bf16.h>

// B=4, N=256, F=64, H=256, A=16, T=3.  BN=1024 rows.
// bf16 inputs (runtime-verified); adjacency int32.
// GEMMs: bf16 MFMA 16x16x32. Weights are EXACT in bf16 (inputs are bf16).
// Precision: activations h/Ehat stored as split hi/lo bf16 pairs along K,
// weights duplicated along K -> A_hi@B + A_lo@B in one MFMA GEMM (~fp32 acc).
// R1: agg.gi fused via precomputed Wg = W2hat.Wih (3-term split-K, K=864).
// R2: 311us. R3/R4: megakernel abandoned (grid barrier >= 25us).
// R5: convwg/prenet/gigru fusion, 337us. R6: 352us; PMC: gigru(128blk) = 72us
//     x3 = 60% of total. Occ 3.3%, hbm 190GB/s, FETCH 12.3MB: 8 colgroups of
//     each row-panel land on 8 different XCDs -> Ehat re-fetched ~8x from HBM.
// R7: (1) K-dedup: Ehat [Eh|El] (576), WgT [hi|lo] (576), WcatT [1280][256];
//         staging source-offset remap; MFMA sequence bitwise identical.
//     (2) gigru back to 64 blocks (16rg x 4cg rg-major: A x4, B x2 repl).
//     (3) register-prefetch pipeline (issue k+1 loads during k compute) in
//         gigru + hcat GEMM; hcat grid bm-inner so H2 fetched once per XCD.

typedef unsigned short ushort_t;
typedef short bf8_t __attribute__((ext_vector_type(8)));
typedef float f4_t  __attribute__((ext_vector_type(4)));

#define BN_ROWS 1024

// ---- bf16 regions (USHORT offsets) ----
#define UB_NFB    0         // 65536   NF [1024][64] (exact)
#define UB_PW1T   65536     // 16384   preW1^T [256][64]
#define UB_PW2T   81920     // 65536   preW2^T [256][256]
#define UB_WCATT  147456    // 327680  Wcat^T [1280][256] (dedup: k&255)
#define UB_WGT    475136    // 442368  Wg^T [768][576] = [hi(288)|lo(288)]
#define UB_H2     917504    // 524288  h  [1024][512] hi|lo
#define UB_EHAT2  1441792   // 589824  Ehat [1024][576] = [Eh(288)|El(288)]
// end 2031616 ushorts = 1015808 floats

// ---- fp32 regions (FLOAT offsets) ----
#define F_PREB1   1015808   // 256
#define F_PREB2   1016064   // 256
#define F_BCAT    1016320   // 1280  [msg_b1 | 0 | gru_bhh]
#define F_BIH     1017600   // 768
#define F_ROW1    1018368   // 65536
#define F_ROB1    1083904   // 256
#define F_ROW2    1084160   // 4096
#define F_ROB2    1088256   // 16
#define F_H       1088272   // 262144
#define F_HCAT    1350416   // 1310720 [hi_p | hj | gh]
#define F_FLAG    2661136   // 1 int
#define F_GCNT    2661140   // 4 ints: per-graph readout arrival counters

// ---- convert index space ----
#define CVa 65536     // end NFB
#define CVb 81920     // end PW1T
#define CVc 147456    // end PW2T
#define CVd 475136    // end WCATT (1280*256)
#define CV_TOTAL 547600   // + 72464 fp32 tail
#define NCONV 1070        // convert blocks (2 elems/thread); wg blocks follow

__device__ __forceinline__ float bf2f(ushort_t u) {
    return __uint_as_float(((unsigned int)u) << 16);
}
__device__ __forceinline__ ushort_t f2b(float v) {
    __hip_bfloat16 b = __float2bfloat16(v);
    return *reinterpret_cast<ushort_t*>(&b);
}
__device__ __forceinline__ float relu(float v) { return v < 0.f ? 0.f : v; }  // NaN-propagating
__device__ __forceinline__ float ld(const void* p, int i, int isf32) {
    return isf32 ? ((const float*)p)[i] : bf2f(((const ushort_t*)p)[i]);
}

// detect + convert (blocks [0,NCONV)) + wg (blocks [NCONV,NCONV+216)).
__global__ __launch_bounds__(256) void convwg_kernel(
    const void* nf, const void* preW1, const void* preb1, const void* preW2, const void* preb2,
    const void* msgW1, const void* msgb1, const void* msgW2, const void* msgb2,
    const void* gruWih, const void* gruWhh, const void* grubih, const void* grubhh,
    const void* roW1, const void* rob1, const void* roW2, const void* rob2,
    float* __restrict__ w)
{
    __shared__ float w2s[4 * 256];
    __shared__ int cnt;
    const int t = threadIdx.x;
    ushort_t* wb = (ushort_t*)w;

    // ---- inline detect (redundant per block; 4KB L2-hit scan) ----
    if (t == 0) cnt = 0;
    __syncthreads();
    {
        const ushort_t* nf0 = (const ushort_t*)nf;
        int bad = 0;
        for (int i = 0; i < 8; ++i) {
            ushort_t u = nf0[(t * 8 + i) * 2];
            int ex = (u >> 7) & 0xFF;
            if ((u & 0x7fff) != 0 && (ex < 100 || ex > 140)) bad++;
        }
        atomicAdd(&cnt, bad);
    }
    __syncthreads();
    const int f32 = (cnt > 512) ? 1 : 0;

    if (blockIdx.x == 0) {          // publish flag + zero readout counters
        if (t < 4) ((int*)(w + F_GCNT))[t] = 0;
        if (t == 4) *(int*)(w + F_FLAG) = f32;
    }

    if (blockIdx.x < NCONV) {
        const int e0 = (blockIdx.x * 256 + t) * 2;
#pragma unroll
        for (int u2 = 0; u2 < 2; ++u2) {
            int e = e0 + u2;
            if (e >= CV_TOTAL) break;
            if (e < CVa) {                                    // NF
                wb[UB_NFB + e] = f2b(ld(nf, e, f32));
            } else if (e < CVb) {                             // preW1^T [256][64]
                int i = e - CVa; int n = i >> 6, k = i & 63;
                wb[UB_PW1T + i] = f2b(ld(preW1, k * 256 + n, f32));
            } else if (e < CVc) {                             // preW2^T [256][256]
                int i = e - CVb; int n = i >> 8, k = i & 255;
                wb[UB_PW2T + i] = f2b(ld(preW2, k * 256 + n, f32));
            } else if (e < CVd) {                             // Wcat^T [1280][256]
                int i = e - CVc; int n = i >> 8, k = i & 255;
                float v;
                if (n < 256)      v = ld(msgW1, k * 256 + n, f32);
                else if (n < 512) v = ld(msgW1, (256 + k) * 256 + (n - 256), f32);
                else              v = ld(gruWhh, k * 768 + (n - 512), f32);
                wb[UB_WCATT + i] = f2b(v);
            } else {                                          // fp32 tail
                int f = e - CVd;
                float v;
                if (f < 256)        v = ld(preb1, f, f32);
                else if (f < 512)   v = ld(preb2, f - 256, f32);
                else if (f < 1792) {
                    int c = f - 512;
                    if (c < 256)      v = ld(msgb1, c, f32);
                    else if (c < 512) v = 0.f;
                    else              v = ld(grubhh, c - 512, f32);
                }
                else if (f < 2560)  v = ld(grubih, f - 1792, f32);
                else if (f < 68096) v = ld(roW1, f - 2560, f32);
                else if (f < 68352) v = ld(rob1, f - 68096, f32);
                else if (f < 72448) v = ld(roW2, f - 68352, f32);
                else                v = ld(rob2, f - 72448, f32);
                w[F_PREB1 + f] = v;
            }
        }
        return;
    }

    // ---- wg path: Wg[k][p] = sum_n W2hat[k][n]*Wih[n][p] -> WgT[p][576] ----
    const int wt = blockIdx.x - NCONV;   // [0,216)
    const int p0 = (wt % 3) * 256;
    const int k0 = (wt / 3) * 4;
    for (int i = t; i < 4 * 256; i += 256) {
        int r = i >> 8, n = i & 255;
        int krow = k0 + r;
        float v;
        if (krow < 256)       v = ld(msgW2, krow * 256 + n, f32);
        else if (krow == 256) v = ld(msgb2, n, f32);
        else                  v = 0.f;
        w2s[i] = v;
    }
    __syncthreads();
    const int p = p0 + t;
    float acc4[4] = {};
    for (int n0 = 0; n0 < 256; n0 += 32) {
        float wv[32];
#pragma unroll
        for (int i = 0; i < 32; ++i)
            wv[i] = ld(gruWih, (n0 + i) * 768 + p, f32);
#pragma unroll
        for (int r = 0; r < 4; ++r) {
            float acc = acc4[r];
#pragma unroll
            for (int q = 0; q < 8; ++q) {
                f4_t w4 = *(const f4_t*)&w2s[r * 256 + n0 + q * 4];
                acc += w4[0] * wv[q * 4 + 0] + w4[1] * wv[q * 4 + 1]
                     + w4[2] * wv[q * 4 + 2] + w4[3] * wv[q * 4 + 3];
            }
            acc4[r] = acc;
        }
    }
#pragma unroll
    for (int r = 0; r < 4; ++r) {
        int krow = k0 + r;
        ushort_t hi = f2b(acc4[r]);
        ushort_t lo = f2b(acc4[r] - bf2f(hi));
        wb[UB_WGT + p * 576 + krow] = hi;
        wb[UB_WGT + p * 576 + 288 + krow] = lo;
    }
}

// Fused pre-net: X = relu(NF@preW1+b1) (in LDS), h = X@preW2+b2.
// 32 blocks x 32 rows; wave w: rows (w&1)*16, cols (w>>1)*128 (8 n-frags).
__global__ __launch_bounds__(256) void prenet_kernel(float* __restrict__ w)
{
    __shared__ ushort_t As[32 * 64];    // NF tile      4KB
    __shared__ ushort_t Xs[32 * 256];   // X tile      16KB
    __shared__ ushort_t Bs[256 * 32];   // weight slab 16KB
    ushort_t* wb = (ushort_t*)w;
    const int t = threadIdx.x;
    const int wave = t >> 6, lane = t & 63;
    const int ln = lane & 15, quad = lane >> 4;
    const int wr = (wave & 1) * 16, wc = (wave >> 1) * 128;
    const int rbase = blockIdx.x * 32;
    const int srow = t >> 2, skc = (t & 3) << 3;

    // stage NF tile [32][64]: 1 bf8 per thread
    {
        int row = t >> 3, kc = (t & 7) << 3;
        *(bf8_t*)(&As[row * 64 + kc]) =
            *(const bf8_t*)(&wb[UB_NFB + (rbase + row) * 64 + kc]);
    }

    f4_t acc[8] = {};
    // phase A: X = relu(NF @ PW1T + b1), K=64
    for (int k0 = 0; k0 < 64; k0 += 32) {
        __syncthreads();
#pragma unroll
        for (int rr = 0; rr < 4; ++rr) {
            int n = srow + 64 * rr;
            *(bf8_t*)(&Bs[n * 32 + skc]) =
                *(const bf8_t*)(&wb[UB_PW1T + n * 64 + k0 + skc]);
        }
        __syncthreads();
        bf8_t af = *(const bf8_t*)(&As[(wr + ln) * 64 + k0 + quad * 8]);
#pragma unroll
        for (int n = 0; n < 8; ++n) {
            bf8_t bfr = *(const bf8_t*)(&Bs[(wc + n * 16 + ln) * 32 + quad * 8]);
            acc[n] = __builtin_amdgcn_mfma_f32_16x16x32_bf16(af, bfr, acc[n], 0, 0, 0);
        }
    }
    __syncthreads();
#pragma unroll
    for (int n = 0; n < 8; ++n) {
        int col = wc + n * 16 + ln;
        float bb = w[F_PREB1 + col];
#pragma unroll
        for (int r = 0; r < 4; ++r) {
            int row = wr + quad * 4 + r;
            Xs[row * 256 + col] = f2b(relu(acc[n][r] + bb));
        }
        acc[n] = (f4_t){0.f, 0.f, 0.f, 0.f};
    }
    __syncthreads();

    // phase B: h = X @ PW2T + b2, K=256
    for (int k0 = 0; k0 < 256; k0 += 32) {
        __syncthreads();
#pragma unroll
        for (int rr = 0; rr < 4; ++rr) {
            int n = srow + 64 * rr;
            *(bf8_t*)(&Bs[n * 32 + skc]) =
                *(const bf8_t*)(&wb[UB_PW2T + n * 256 + k0 + skc]);
        }
        __syncthreads();
        bf8_t af = *(const bf8_t*)(&Xs[(wr + ln) * 256 + k0 + quad * 8]);
#pragma unroll
        for (int n = 0; n < 8; ++n) {
            bf8_t bfr = *(const bf8_t*)(&Bs[(wc + n * 16 + ln) * 32 + quad * 8]);
            acc[n] = __builtin_amdgcn_mfma_f32_16x16x32_bf16(af, bfr, acc[n], 0, 0, 0);
        }
    }
#pragma unroll
    for (int n = 0; n < 8; ++n) {
        int col = wc + n * 16 + ln;
        float bb = w[F_PREB2 + col];
#pragma unroll
        for (int r = 0; r < 4; ++r) {
            int grow = rbase + wr + quad * 4 + r;
            float v = acc[n][r] + bb;
            w[F_H + grow * 256 + col] = v;
            ushort_t hi = f2b(v);
            wb[UB_H2 + grow * 512 + col] = hi;
            wb[UB_H2 + grow * 512 + 256 + col] = f2b(v - bf2f(hi));
        }
    }
}

// hcat GEMM: C[1024,1280] = H2[1024,512] @ WcatT[1280,256 dedup]^T + bias.
// 64x128 tiles, 1D grid 160 (bm-inner: same-bm blocks share XCD -> A once).
// Register-prefetch pipeline: k+1 tiles loaded during k compute.
__global__ __launch_bounds__(256) void hcat_kernel(float* __restrict__ w)
{
    __shared__ ushort_t As[64 * 32];
    __shared__ ushort_t Bs[128 * 32];
    ushort_t* wb = (ushort_t*)w;
    const ushort_t* A  = wb + UB_H2;
    const ushort_t* Bt = wb + UB_WCATT;
    const int t = threadIdx.x;
    const int wave = t >> 6, lane = t & 63;
    const int ln = lane & 15, quad = lane >> 4;
    const int bm = (blockIdx.x & 15) * 64, bn = (blockIdx.x >> 4) * 128;
    const int wm = (wave >> 1) * 32, wn = (wave & 1) * 64;
    const int srow = t >> 2, skc = (t & 3) << 3;

    f4_t acc[2][4] = {};
    bf8_t ra, rb[2];

    // prologue: load k0=0
    ra = *(const bf8_t*)(&A[(bm + srow) * 512 + skc]);
#pragma unroll
    for (int r = 0; r < 2; ++r)
        rb[r] = *(const bf8_t*)(&Bt[(bn + srow + r * 64) * 256 + skc]);

    for (int ks = 0; ks < 16; ++ks) {
        __syncthreads();
        *(bf8_t*)(&As[srow * 32 + skc]) = ra;
#pragma unroll
        for (int r = 0; r < 2; ++r)
            *(bf8_t*)(&Bs[(srow + r * 64) * 32 + skc]) = rb[r];
        __syncthreads();
        if (ks < 15) {
            int k0 = (ks + 1) * 32;
            ra = *(const bf8_t*)(&A[(bm + srow) * 512 + k0 + skc]);
            int kb = (k0 & 255);
#pragma unroll
            for (int r = 0; r < 2; ++r)
                rb[r] = *(const bf8_t*)(&Bt[(bn + srow + r * 64) * 256 + kb + skc]);
        }
        bf8_t af[2], bfr[4];
#pragma unroll
        for (int i = 0; i < 2; ++i)
            af[i]  = *(const bf8_t*)(&As[(wm + i * 16 + ln) * 32 + quad * 8]);
#pragma unroll
        for (int i = 0; i < 4; ++i)
            bfr[i] = *(const bf8_t*)(&Bs[(wn + i * 16 + ln) * 32 + quad * 8]);
#pragma unroll
        for (int mi = 0; mi < 2; ++mi)
#pragma unroll
            for (int ni = 0; ni < 4; ++ni)
                acc[mi][ni] = __builtin_amdgcn_mfma_f32_16x16x32_bf16(
                    af[mi], bfr[ni], acc[mi][ni], 0, 0, 0);
    }

#pragma unroll
    for (int mi = 0; mi < 2; ++mi) {
#pragma unroll
        for (int ni = 0; ni < 4; ++ni) {
            int col = bn + wn + ni * 16 + ln;
            float bb = w[F_BCAT + col];
#pragma unroll
            for (int r = 0; r < 4; ++r) {
                int row = bm + wm + mi * 16 + quad * 4 + r;
                w[F_HCAT + row * 1280 + col] = acc[mi][ni][r] + bb;
            }
        }
    }
}

// Ehat[row] (width 576): [ sum relu(hi_p+hj) hi (256) | deg | 0 | lo (256) | 0 ]
__global__ __launch_bounds__(256) void msg_kernel(
    const float* __restrict__ hcat,   // [1024][1280]: [hi_p | hj | gh]
    const int*   __restrict__ adj,    // [1024][256]
    ushort_t* __restrict__ ehat)      // [1024][576]
{
    const int row = blockIdx.x;
    const int t = threadIdx.x;
    __shared__ int ej[256];
    __shared__ int ecnt;
    if (t == 0) ecnt = 0;
    __syncthreads();
    if (adj[row * 256 + t]) { int p = atomicAdd(&ecnt, 1); ej[p] = t; }
    const float hi = hcat[row * 1280 + t];
    const float* hjb = hcat + (row >> 8) * 256 * 1280 + 256;
    __syncthreads();
    const int ne = ecnt;
    float acc = 0.f;
#pragma unroll 4
    for (int p = 0; p < ne; ++p) {
        int j = ej[p];
        acc += relu(hi + hjb[j * 1280 + t]);
    }
    ushort_t h16 = f2b(acc);
    ushort_t l16 = f2b(acc - bf2f(h16));
    ushort_t* er = ehat + row * 576;
    er[t] = h16;
    er[288 + t] = l16;
    if (t < 32) {
        er[256 + t] = f2b(t == 0 ? (float)ne : 0.f);  // deg exact (<=256)
        er[544 + t] = 0;
    }
}

// Fused gi-GEMM + GRU.  64 blocks = 16 rowgroups x 4 colgroups (rg-major).
// gi = Ehat @ Wg + bih; logical K=864 = [Eh@hi | El@hi | Eh@lo] with dedup'd
// storage (A 576-wide, B 576-wide) via source-offset remap. GRU in epilogue.
// Register-prefetch pipeline. FINAL: last block per graph does readout.
template<int FINAL>
__global__ __launch_bounds__(256) void gigru_kernel(float* __restrict__ w,
                                                    void* __restrict__ out)
{
    __shared__ ushort_t As[64 * 32];    // 4KB
    __shared__ ushort_t Bs[192 * 32];   // 12KB
    __shared__ float gl[256];
    __shared__ float t1[256];
    __shared__ int donef;
    ushort_t* wb = (ushort_t*)w;
    const int t = threadIdx.x;
    const int wave = t >> 6, lane = t & 63;
    const int ln = lane & 15, quad = lane >> 4;
    const int rg = blockIdx.x >> 2, cg = blockIdx.x & 3;
    const int rbase = rg * 64;
    const int srow = t >> 2, skc = (t & 3) << 3;

    const ushort_t* Ap = wb + UB_EHAT2 + (rbase + srow) * 576 + skc;
    // B row for staging slot br: wrow = gate*256 + cg*64 + (br&63)
    int browoff[3];
#pragma unroll
    for (int rr = 0; rr < 3; ++rr) {
        int br = srow + 64 * rr;
        browoff[rr] = ((br >> 6) * 256 + cg * 64 + (br & 63)) * 576 + skc;
    }
    const ushort_t* Bp = wb + UB_WGT;

    f4_t acc[12] = {};
    bf8_t ra, rb[3];

    // k-offset remaps (k0 multiple of 32):
    //   aoff: [0,576)->k0, [576,864)->k0-576   (Eh reused)
    //   boff: [0,288)->k0, [288,864)->k0-288   (hi reused)
    ra = *(const bf8_t*)(Ap);
#pragma unroll
    for (int rr = 0; rr < 3; ++rr)
        rb[rr] = *(const bf8_t*)(&Bp[browoff[rr]]);

    for (int ks = 0; ks < 27; ++ks) {
        __syncthreads();
        *(bf8_t*)(&As[srow * 32 + skc]) = ra;
#pragma unroll
        for (int rr = 0; rr < 3; ++rr)
            *(bf8_t*)(&Bs[(srow + 64 * rr) * 32 + skc]) = rb[rr];
        __syncthreads();
        if (ks < 26) {
            int k0 = (ks + 1) * 32;
            int ka = (k0 < 576) ? k0 : k0 - 576;
            int kb = (k0 < 288) ? k0 : k0 - 288;
            ra = *(const bf8_t*)(&Ap[ka]);
#pragma unroll
            for (int rr = 0; rr < 3; ++rr)
                rb[rr] = *(const bf8_t*)(&Bp[browoff[rr] + kb]);
        }
        bf8_t af = *(const bf8_t*)(&As[(wave * 16 + ln) * 32 + quad * 8]);
#pragma unroll
        for (int n = 0; n < 12; ++n) {
            bf8_t bfr = *(const bf8_t*)(&Bs[(n * 16 + ln) * 32 + quad * 8]);
            acc[n] = __builtin_amdgcn_mfma_f32_16x16x32_bf16(af, bfr, acc[n], 0, 0, 0);
        }
    }

    // GRU epilogue: n 0..3 = ir frags, 4..7 = iz, 8..11 = in (same col set).
#pragma unroll
    for (int n = 0; n < 4; ++n) {
        int col = cg * 64 + n * 16 + ln;
        float bi_r = w[F_BIH + col];
        float bi_z = w[F_BIH + 256 + col];
        float bi_n = w[F_BIH + 512 + col];
#pragma unroll
        for (int r = 0; r < 4; ++r) {
            int row = rbase + wave * 16 + quad * 4 + r;
            float ir = acc[n][r] + bi_r;
            float iz = acc[n + 4][r] + bi_z;
            float in = acc[n + 8][r] + bi_n;
            const float* ghr = w + F_HCAT + row * 1280 + 512;
            float hr = ghr[col], hz = ghr[256 + col], hn = ghr[512 + col];
            float rg_ = 1.f / (1.f + __expf(-(ir + hr)));
            float z   = 1.f / (1.f + __expf(-(iz + hz)));
            float nn  = tanhf(in + rg_ * hn);
            float ho = w[F_H + row * 256 + col];
            float hv = (1.f - z) * nn + z * ho;
            w[F_H + row * 256 + col] = hv;
            if (!FINAL) {
                ushort_t hb = f2b(hv);
                wb[UB_H2 + row * 512 + col] = hb;
                wb[UB_H2 + row * 512 + 256 + col] = f2b(hv - bf2f(hb));
            }
        }
    }

    if (FINAL) {
        // per-graph arrival counter: 16 blocks/graph; last one does readout.
        const int g = blockIdx.x >> 4;
        __syncthreads();
        if (t == 0) {
            __threadfence();                           // release h writes
            int prev = atomicAdd((int*)(w + F_GCNT) + g, 1);
            donef = (prev == 15);
        }
        __syncthreads();
        if (!donef) return;
        __threadfence();                               // acquire others' h

        const float* hb = w + F_H + g * 256 * 256;
        float s = 0.f;
        for (int n = 0; n < 256; ++n) s += hb[n * 256 + t];
        gl[t] = s;
        __syncthreads();
        float acc1 = w[F_ROB1 + t];
        for (int k = 0; k < 256; ++k) acc1 += gl[k] * w[F_ROW1 + k * 256 + t];
        t1[t] = relu(acc1);
        __syncthreads();
        if (t < 16) {
            float q = w[F_ROB2 + t];
            for (int k = 0; k < 256; ++k) q += t1[k] * w[F_ROW2 + k * 16 + t];
            if (*(const int*)(w + F_FLAG)) ((float*)out)[g * 16 + t] = q;
            else ((__hip_bfloat16*)out)[g * 16 + t] = __float2bfloat16(q);
        }
    }
}

extern "C" void kernel_launch(void* const* d_in, const int* in_sizes, int n_in,
                              void* d_out, int out_size, void* d_ws, size_t ws_size,
                              hipStream_t stream) {
    float* w = (float*)d_ws;
    ushort_t* wb = (ushort_t*)d_ws;

    static const int dictSz[18]  = {65536,262144,16384,256,65536,256,131072,256,65536,256,
                                    196608,196608,768,768,65536,256,4096,16};
    static const int alphaSz[18] = {262144,196608,196608,768,768,131072,65536,256,256,
                                    65536,16384,65536,256,256,65536,4096,256,16};
    static const int alphaPos[18] = {9,0,10,12,11,13,5,7,6,8,2,1,4,3,14,16,15,17};
    bool dictOK = true, alphaOK = true;
    for (int i = 0; i < 18 && i < n_in; ++i) {
        if (in_sizes[i] != dictSz[i])  dictOK = false;
        if (in_sizes[i] != alphaSz[i]) alphaOK = false;
    }
    const void* P[18];
    for (int l = 0; l < 18; ++l) P[l] = d_in[(!dictOK && alphaOK) ? alphaPos[l] : l];
    const int* adj = (const int*)P[1];

    convwg_kernel<<<NCONV + 216, 256, 0, stream>>>(
        P[0], P[2], P[3], P[4], P[5], P[6], P[7], P[8], P[9],
        P[10], P[11], P[12], P[13], P[14], P[15], P[16], P[17], w);

    prenet_kernel<<<32, 256, 0, stream>>>(w);

    for (int it = 0; it < 3; ++it) {
        hcat_kernel<<<160, 256, 0, stream>>>(w);
        msg_kernel<<<BN_ROWS, 256, 0, stream>>>(w + F_HCAT, adj, wb + UB_EHAT2);
        if (it < 2)
            gigru_kernel<0><<<64, 256, 0, stream>>>(w, d_out);
        else
            gigru_kernel<1><<<64, 256, 0, stream>>>(w, d_out);
    }
}

// Round 8
// 297.275 us; speedup vs baseline: 1.1861x; 1.0391x over previous
//
#include <hip/hip_runtime.h>
#include <hip/hip_bf16.h>

// B=4, N=256, F=64, H=256, A=16, T=3.  BN=1024 rows.
// bf16 inputs (runtime-verified); adjacency int32.
// GEMMs: bf16 MFMA 16x16x32. Weights are EXACT in bf16 (inputs are bf16).
// Precision: activations h/Ehat stored as split hi/lo bf16 pairs along K,
// weights duplicated along K -> A_hi@B + A_lo@B in one MFMA GEMM (~fp32 acc).
// R1: agg.gi fused via Wg = W2hat.Wih. R2: 311us. R3/R4: megakernel abandoned.
// R5/R6: convwg/prenet/gigru fusion. R7: K-dedup + 64blk + reg-prefetch ->
//     308.9us; gigru 53us x3 = 52%, latency-bound (Occ 1.5%, 132GB/s, 27
//     serialized k-rounds, 8-way LDS conflicts on 64B-stride slab).
// R8: shorten the k-chain: (1) BK 32->96 gigru (9 rounds), BK=64 hcat (8);
//     (2) LDS pad stride 104u/72u -> 2-way (free) fragment reads;
//     (3) gigru XCD-dedup mapping (A panel read by exactly one XCD).
//     MFMA (k,n) order unchanged -> bitwise-identical output.

typedef unsigned short ushort_t;
typedef short bf8_t __attribute__((ext_vector_type(8)));
typedef float f4_t  __attribute__((ext_vector_type(4)));

#define BN_ROWS 1024

// ---- bf16 regions (USHORT offsets) ----
#define UB_NFB    0         // 65536   NF [1024][64] (exact)
#define UB_PW1T   65536     // 16384   preW1^T [256][64]
#define UB_PW2T   81920     // 65536   preW2^T [256][256]
#define UB_WCATT  147456    // 327680  Wcat^T [1280][256] (dedup: k&255)
#define UB_WGT    475136    // 442368  Wg^T [768][576] = [hi(288)|lo(288)]
#define UB_H2     917504    // 524288  h  [1024][512] hi|lo
#define UB_EHAT2  1441792   // 589824  Ehat [1024][576] = [Eh(288)|El(288)]
// end 2031616 ushorts = 1015808 floats

// ---- fp32 regions (FLOAT offsets) ----
#define F_PREB1   1015808   // 256
#define F_PREB2   1016064   // 256
#define F_BCAT    1016320   // 1280  [msg_b1 | 0 | gru_bhh]
#define F_BIH     1017600   // 768
#define F_ROW1    1018368   // 65536
#define F_ROB1    1083904   // 256
#define F_ROW2    1084160   // 4096
#define F_ROB2    1088256   // 16
#define F_H       1088272   // 262144
#define F_HCAT    1350416   // 1310720 [hi_p | hj | gh]
#define F_FLAG    2661136   // 1 int
#define F_GCNT    2661140   // 4 ints: per-graph readout arrival counters

// ---- convert index space ----
#define CVa 65536     // end NFB
#define CVb 81920     // end PW1T
#define CVc 147456    // end PW2T
#define CVd 475136    // end WCATT (1280*256)
#define CV_TOTAL 547600   // + 72464 fp32 tail
#define NCONV 1070        // convert blocks (2 elems/thread); wg blocks follow

__device__ __forceinline__ float bf2f(ushort_t u) {
    return __uint_as_float(((unsigned int)u) << 16);
}
__device__ __forceinline__ ushort_t f2b(float v) {
    __hip_bfloat16 b = __float2bfloat16(v);
    return *reinterpret_cast<ushort_t*>(&b);
}
__device__ __forceinline__ float relu(float v) { return v < 0.f ? 0.f : v; }  // NaN-propagating
__device__ __forceinline__ float ld(const void* p, int i, int isf32) {
    return isf32 ? ((const float*)p)[i] : bf2f(((const ushort_t*)p)[i]);
}

// detect + convert (blocks [0,NCONV)) + wg (blocks [NCONV,NCONV+216)).
__global__ __launch_bounds__(256) void convwg_kernel(
    const void* nf, const void* preW1, const void* preb1, const void* preW2, const void* preb2,
    const void* msgW1, const void* msgb1, const void* msgW2, const void* msgb2,
    const void* gruWih, const void* gruWhh, const void* grubih, const void* grubhh,
    const void* roW1, const void* rob1, const void* roW2, const void* rob2,
    float* __restrict__ w)
{
    __shared__ float w2s[4 * 256];
    __shared__ int cnt;
    const int t = threadIdx.x;
    ushort_t* wb = (ushort_t*)w;

    // ---- inline detect (redundant per block; 4KB L2-hit scan) ----
    if (t == 0) cnt = 0;
    __syncthreads();
    {
        const ushort_t* nf0 = (const ushort_t*)nf;
        int bad = 0;
        for (int i = 0; i < 8; ++i) {
            ushort_t u = nf0[(t * 8 + i) * 2];
            int ex = (u >> 7) & 0xFF;
            if ((u & 0x7fff) != 0 && (ex < 100 || ex > 140)) bad++;
        }
        atomicAdd(&cnt, bad);
    }
    __syncthreads();
    const int f32 = (cnt > 512) ? 1 : 0;

    if (blockIdx.x == 0) {          // publish flag + zero readout counters
        if (t < 4) ((int*)(w + F_GCNT))[t] = 0;
        if (t == 4) *(int*)(w + F_FLAG) = f32;
    }

    if (blockIdx.x < NCONV) {
        const int e0 = (blockIdx.x * 256 + t) * 2;
#pragma unroll
        for (int u2 = 0; u2 < 2; ++u2) {
            int e = e0 + u2;
            if (e >= CV_TOTAL) break;
            if (e < CVa) {                                    // NF
                wb[UB_NFB + e] = f2b(ld(nf, e, f32));
            } else if (e < CVb) {                             // preW1^T [256][64]
                int i = e - CVa; int n = i >> 6, k = i & 63;
                wb[UB_PW1T + i] = f2b(ld(preW1, k * 256 + n, f32));
            } else if (e < CVc) {                             // preW2^T [256][256]
                int i = e - CVb; int n = i >> 8, k = i & 255;
                wb[UB_PW2T + i] = f2b(ld(preW2, k * 256 + n, f32));
            } else if (e < CVd) {                             // Wcat^T [1280][256]
                int i = e - CVc; int n = i >> 8, k = i & 255;
                float v;
                if (n < 256)      v = ld(msgW1, k * 256 + n, f32);
                else if (n < 512) v = ld(msgW1, (256 + k) * 256 + (n - 256), f32);
                else              v = ld(gruWhh, k * 768 + (n - 512), f32);
                wb[UB_WCATT + i] = f2b(v);
            } else {                                          // fp32 tail
                int f = e - CVd;
                float v;
                if (f < 256)        v = ld(preb1, f, f32);
                else if (f < 512)   v = ld(preb2, f - 256, f32);
                else if (f < 1792) {
                    int c = f - 512;
                    if (c < 256)      v = ld(msgb1, c, f32);
                    else if (c < 512) v = 0.f;
                    else              v = ld(grubhh, c - 512, f32);
                }
                else if (f < 2560)  v = ld(grubih, f - 1792, f32);
                else if (f < 68096) v = ld(roW1, f - 2560, f32);
                else if (f < 68352) v = ld(rob1, f - 68096, f32);
                else if (f < 72448) v = ld(roW2, f - 68352, f32);
                else                v = ld(rob2, f - 72448, f32);
                w[F_PREB1 + f] = v;
            }
        }
        return;
    }

    // ---- wg path: Wg[k][p] = sum_n W2hat[k][n]*Wih[n][p] -> WgT[p][576] ----
    const int wt = blockIdx.x - NCONV;   // [0,216)
    const int p0 = (wt % 3) * 256;
    const int k0 = (wt / 3) * 4;
    for (int i = t; i < 4 * 256; i += 256) {
        int r = i >> 8, n = i & 255;
        int krow = k0 + r;
        float v;
        if (krow < 256)       v = ld(msgW2, krow * 256 + n, f32);
        else if (krow == 256) v = ld(msgb2, n, f32);
        else                  v = 0.f;
        w2s[i] = v;
    }
    __syncthreads();
    const int p = p0 + t;
    float acc4[4] = {};
    for (int n0 = 0; n0 < 256; n0 += 32) {
        float wv[32];
#pragma unroll
        for (int i = 0; i < 32; ++i)
            wv[i] = ld(gruWih, (n0 + i) * 768 + p, f32);
#pragma unroll
        for (int r = 0; r < 4; ++r) {
            float acc = acc4[r];
#pragma unroll
            for (int q = 0; q < 8; ++q) {
                f4_t w4 = *(const f4_t*)&w2s[r * 256 + n0 + q * 4];
                acc += w4[0] * wv[q * 4 + 0] + w4[1] * wv[q * 4 + 1]
                     + w4[2] * wv[q * 4 + 2] + w4[3] * wv[q * 4 + 3];
            }
            acc4[r] = acc;
        }
    }
#pragma unroll
    for (int r = 0; r < 4; ++r) {
        int krow = k0 + r;
        ushort_t hi = f2b(acc4[r]);
        ushort_t lo = f2b(acc4[r] - bf2f(hi));
        wb[UB_WGT + p * 576 + krow] = hi;
        wb[UB_WGT + p * 576 + 288 + krow] = lo;
    }
}

// Fused pre-net: X = relu(NF@preW1+b1) (in LDS), h = X@preW2+b2.
// 32 blocks x 32 rows; wave w: rows (w&1)*16, cols (w>>1)*128 (8 n-frags).
__global__ __launch_bounds__(256) void prenet_kernel(float* __restrict__ w)
{
    __shared__ ushort_t As[32 * 64];    // NF tile      4KB
    __shared__ ushort_t Xs[32 * 256];   // X tile      16KB
    __shared__ ushort_t Bs[256 * 32];   // weight slab 16KB
    ushort_t* wb = (ushort_t*)w;
    const int t = threadIdx.x;
    const int wave = t >> 6, lane = t & 63;
    const int ln = lane & 15, quad = lane >> 4;
    const int wr = (wave & 1) * 16, wc = (wave >> 1) * 128;
    const int rbase = blockIdx.x * 32;
    const int srow = t >> 2, skc = (t & 3) << 3;

    // stage NF tile [32][64]: 1 bf8 per thread
    {
        int row = t >> 3, kc = (t & 7) << 3;
        *(bf8_t*)(&As[row * 64 + kc]) =
            *(const bf8_t*)(&wb[UB_NFB + (rbase + row) * 64 + kc]);
    }

    f4_t acc[8] = {};
    // phase A: X = relu(NF @ PW1T + b1), K=64
    for (int k0 = 0; k0 < 64; k0 += 32) {
        __syncthreads();
#pragma unroll
        for (int rr = 0; rr < 4; ++rr) {
            int n = srow + 64 * rr;
            *(bf8_t*)(&Bs[n * 32 + skc]) =
                *(const bf8_t*)(&wb[UB_PW1T + n * 64 + k0 + skc]);
        }
        __syncthreads();
        bf8_t af = *(const bf8_t*)(&As[(wr + ln) * 64 + k0 + quad * 8]);
#pragma unroll
        for (int n = 0; n < 8; ++n) {
            bf8_t bfr = *(const bf8_t*)(&Bs[(wc + n * 16 + ln) * 32 + quad * 8]);
            acc[n] = __builtin_amdgcn_mfma_f32_16x16x32_bf16(af, bfr, acc[n], 0, 0, 0);
        }
    }
    __syncthreads();
#pragma unroll
    for (int n = 0; n < 8; ++n) {
        int col = wc + n * 16 + ln;
        float bb = w[F_PREB1 + col];
#pragma unroll
        for (int r = 0; r < 4; ++r) {
            int row = wr + quad * 4 + r;
            Xs[row * 256 + col] = f2b(relu(acc[n][r] + bb));
        }
        acc[n] = (f4_t){0.f, 0.f, 0.f, 0.f};
    }
    __syncthreads();

    // phase B: h = X @ PW2T + b2, K=256
    for (int k0 = 0; k0 < 256; k0 += 32) {
        __syncthreads();
#pragma unroll
        for (int rr = 0; rr < 4; ++rr) {
            int n = srow + 64 * rr;
            *(bf8_t*)(&Bs[n * 32 + skc]) =
                *(const bf8_t*)(&wb[UB_PW2T + n * 256 + k0 + skc]);
        }
        __syncthreads();
        bf8_t af = *(const bf8_t*)(&Xs[(wr + ln) * 256 + k0 + quad * 8]);
#pragma unroll
        for (int n = 0; n < 8; ++n) {
            bf8_t bfr = *(const bf8_t*)(&Bs[(wc + n * 16 + ln) * 32 + quad * 8]);
            acc[n] = __builtin_amdgcn_mfma_f32_16x16x32_bf16(af, bfr, acc[n], 0, 0, 0);
        }
    }
#pragma unroll
    for (int n = 0; n < 8; ++n) {
        int col = wc + n * 16 + ln;
        float bb = w[F_PREB2 + col];
#pragma unroll
        for (int r = 0; r < 4; ++r) {
            int grow = rbase + wr + quad * 4 + r;
            float v = acc[n][r] + bb;
            w[F_H + grow * 256 + col] = v;
            ushort_t hi = f2b(v);
            wb[UB_H2 + grow * 512 + col] = hi;
            wb[UB_H2 + grow * 512 + 256 + col] = f2b(v - bf2f(hi));
        }
    }
}

// hcat GEMM: C[1024,1280] = H2[1024,512] @ WcatT[1280,256 dedup]^T + bias.
// 64x128 tiles, grid 160 bm-inner. BK=64 (8 rounds), LDS row stride 72u
// (144B -> conflict-free frag reads). Register-prefetch distance 1.
#define HLD 72
__global__ __launch_bounds__(256) void hcat_kernel(float* __restrict__ w)
{
    __shared__ ushort_t As[64 * HLD];    // 9.2KB
    __shared__ ushort_t Bs[128 * HLD];   // 18.4KB
    ushort_t* wb = (ushort_t*)w;
    const ushort_t* A  = wb + UB_H2;
    const ushort_t* Bt = wb + UB_WCATT;
    const int t = threadIdx.x;
    const int wave = t >> 6, lane = t & 63;
    const int ln = lane & 15, quad = lane >> 4;
    const int bm = (blockIdx.x & 15) * 64, bn = (blockIdx.x >> 4) * 128;
    const int wm = (wave >> 1) * 32, wn = (wave & 1) * 64;
    const int srow = t >> 2, skc = (t & 3) << 3;

    f4_t acc[2][4] = {};
    bf8_t ra[2], rb[2][2];

    // prologue: load k-block 0 (k = s*32 + skc)
#pragma unroll
    for (int s = 0; s < 2; ++s) {
        ra[s] = *(const bf8_t*)(&A[(bm + srow) * 512 + s * 32 + skc]);
#pragma unroll
        for (int r = 0; r < 2; ++r)
            rb[r][s] = *(const bf8_t*)(&Bt[(bn + srow + r * 64) * 256 + s * 32 + skc]);
    }

    for (int ks = 0; ks < 8; ++ks) {
        __syncthreads();
#pragma unroll
        for (int s = 0; s < 2; ++s) {
            *(bf8_t*)(&As[srow * HLD + s * 32 + skc]) = ra[s];
#pragma unroll
            for (int r = 0; r < 2; ++r)
                *(bf8_t*)(&Bs[(srow + r * 64) * HLD + s * 32 + skc]) = rb[r][s];
        }
        __syncthreads();
        if (ks < 7) {
            int k0 = (ks + 1) * 64;
#pragma unroll
            for (int s = 0; s < 2; ++s) {
                int k = k0 + s * 32;
                ra[s] = *(const bf8_t*)(&A[(bm + srow) * 512 + k + skc]);
                int kb = k & 255;
#pragma unroll
                for (int r = 0; r < 2; ++r)
                    rb[r][s] = *(const bf8_t*)(&Bt[(bn + srow + r * 64) * 256 + kb + skc]);
            }
        }
#pragma unroll
        for (int kk = 0; kk < 2; ++kk) {
            bf8_t af[2], bfr[4];
#pragma unroll
            for (int i = 0; i < 2; ++i)
                af[i]  = *(const bf8_t*)(&As[(wm + i * 16 + ln) * HLD + kk * 32 + quad * 8]);
#pragma unroll
            for (int i = 0; i < 4; ++i)
                bfr[i] = *(const bf8_t*)(&Bs[(wn + i * 16 + ln) * HLD + kk * 32 + quad * 8]);
#pragma unroll
            for (int mi = 0; mi < 2; ++mi)
#pragma unroll
                for (int ni = 0; ni < 4; ++ni)
                    acc[mi][ni] = __builtin_amdgcn_mfma_f32_16x16x32_bf16(
                        af[mi], bfr[ni], acc[mi][ni], 0, 0, 0);
        }
    }

#pragma unroll
    for (int mi = 0; mi < 2; ++mi) {
#pragma unroll
        for (int ni = 0; ni < 4; ++ni) {
            int col = bn + wn + ni * 16 + ln;
            float bb = w[F_BCAT + col];
#pragma unroll
            for (int r = 0; r < 4; ++r) {
                int row = bm + wm + mi * 16 + quad * 4 + r;
                w[F_HCAT + row * 1280 + col] = acc[mi][ni][r] + bb;
            }
        }
    }
}

// Ehat[row] (width 576): [ sum relu(hi_p+hj) hi (256) | deg | 0 | lo (256) | 0 ]
__global__ __launch_bounds__(256) void msg_kernel(
    const float* __restrict__ hcat,   // [1024][1280]: [hi_p | hj | gh]
    const int*   __restrict__ adj,    // [1024][256]
    ushort_t* __restrict__ ehat)      // [1024][576]
{
    const int row = blockIdx.x;
    const int t = threadIdx.x;
    __shared__ int ej[256];
    __shared__ int ecnt;
    if (t == 0) ecnt = 0;
    __syncthreads();
    if (adj[row * 256 + t]) { int p = atomicAdd(&ecnt, 1); ej[p] = t; }
    const float hi = hcat[row * 1280 + t];
    const float* hjb = hcat + (row >> 8) * 256 * 1280 + 256;
    __syncthreads();
    const int ne = ecnt;
    float acc = 0.f;
#pragma unroll 4
    for (int p = 0; p < ne; ++p) {
        int j = ej[p];
        acc += relu(hi + hjb[j * 1280 + t]);
    }
    ushort_t h16 = f2b(acc);
    ushort_t l16 = f2b(acc - bf2f(h16));
    ushort_t* er = ehat + row * 576;
    er[t] = h16;
    er[288 + t] = l16;
    if (t < 32) {
        er[256 + t] = f2b(t == 0 ? (float)ne : 0.f);  // deg exact (<=256)
        er[544 + t] = 0;
    }
}

// Fused gi-GEMM + GRU.  64 blocks, XCD-dedup mapping:
//   xcd=bid&7; cg=xcd&3; rg=(bid>>3)+8*(xcd>>2)  -> each Ehat row-panel read
//   by exactly one XCD (A HBM 4.7->1.2MB); B (221KB/cg) L2-resident per XCD.
// gi = Ehat @ Wg + bih; logical K=864 = [Eh@hi | El@hi | Eh@lo] with dedup'd
// storage via per-32-subblock source remap. BK=96 (9 rounds), LDS stride 104u
// (208B -> conflict-free). GRU in epilogue. FINAL: last block/graph -> readout.
#define GLD 104
template<int FINAL>
__global__ __launch_bounds__(256) void gigru_kernel(float* __restrict__ w,
                                                    void* __restrict__ out)
{
    __shared__ ushort_t As[64 * GLD];    // 13.3KB
    __shared__ ushort_t Bs[192 * GLD];   // 40KB
    __shared__ float gl[256];
    __shared__ float t1[256];
    __shared__ int donef;
    ushort_t* wb = (ushort_t*)w;
    const int t = threadIdx.x;
    const int wave = t >> 6, lane = t & 63;
    const int ln = lane & 15, quad = lane >> 4;
    const int xcd = blockIdx.x & 7;
    const int cg = xcd & 3;
    const int rg = (blockIdx.x >> 3) + 8 * (xcd >> 2);
    const int rbase = rg * 64;
    const int srow = t >> 2, skc = (t & 3) << 3;

    const ushort_t* Ap = wb + UB_EHAT2 + (rbase + srow) * 576 + skc;
    int browoff[3];
#pragma unroll
    for (int rr = 0; rr < 3; ++rr) {
        int br = srow + 64 * rr;
        browoff[rr] = ((br >> 6) * 256 + cg * 64 + (br & 63)) * 576 + skc;
    }
    const ushort_t* Bp = wb + UB_WGT;

    f4_t acc[12] = {};
    bf8_t ra[3], rb[3][3];

    // per-32-subblock k remaps: A [0,576)->k, [576,864)->k-576 (Eh reused)
    //                           B [0,288)->k, [288,864)->k-288 (hi reused)
    // prologue (k0=0: identity)
#pragma unroll
    for (int s = 0; s < 3; ++s) {
        ra[s] = *(const bf8_t*)(&Ap[s * 32]);
#pragma unroll
        for (int rr = 0; rr < 3; ++rr)
            rb[rr][s] = *(const bf8_t*)(&Bp[browoff[rr] + s * 32]);
    }

    for (int ks = 0; ks < 9; ++ks) {
        __syncthreads();
#pragma unroll
        for (int s = 0; s < 3; ++s) {
            *(bf8_t*)(&As[srow * GLD + s * 32 + skc]) = ra[s];
#pragma unroll
            for (int rr = 0; rr < 3; ++rr)
                *(bf8_t*)(&Bs[(srow + 64 * rr) * GLD + s * 32 + skc]) = rb[rr][s];
        }
        __syncthreads();
        if (ks < 8) {
            int k0 = (ks + 1) * 96;
#pragma unroll
            for (int s = 0; s < 3; ++s) {
                int k = k0 + s * 32;
                int ka = (k < 576) ? k : k - 576;
                int kb = (k < 288) ? k : k - 288;
                ra[s] = *(const bf8_t*)(&Ap[ka]);
#pragma unroll
                for (int rr = 0; rr < 3; ++rr)
                    rb[rr][s] = *(const bf8_t*)(&Bp[browoff[rr] + kb]);
            }
        }
#pragma unroll
        for (int kk = 0; kk < 3; ++kk) {
            bf8_t af = *(const bf8_t*)(&As[(wave * 16 + ln) * GLD + kk * 32 + quad * 8]);
#pragma unroll
            for (int n = 0; n < 12; ++n) {
                bf8_t bfr = *(const bf8_t*)(&Bs[(n * 16 + ln) * GLD + kk * 32 + quad * 8]);
                acc[n] = __builtin_amdgcn_mfma_f32_16x16x32_bf16(af, bfr, acc[n], 0, 0, 0);
            }
        }
    }

    // GRU epilogue: n 0..3 = ir frags, 4..7 = iz, 8..11 = in (same col set).
#pragma unroll
    for (int n = 0; n < 4; ++n) {
        int col = cg * 64 + n * 16 + ln;
        float bi_r = w[F_BIH + col];
        float bi_z = w[F_BIH + 256 + col];
        float bi_n = w[F_BIH + 512 + col];
#pragma unroll
        for (int r = 0; r < 4; ++r) {
            int row = rbase + wave * 16 + quad * 4 + r;
            float ir = acc[n][r] + bi_r;
            float iz = acc[n + 4][r] + bi_z;
            float in = acc[n + 8][r] + bi_n;
            const float* ghr = w + F_HCAT + row * 1280 + 512;
            float hr = ghr[col], hz = ghr[256 + col], hn = ghr[512 + col];
            float rg_ = 1.f / (1.f + __expf(-(ir + hr)));
            float z   = 1.f / (1.f + __expf(-(iz + hz)));
            float nn  = tanhf(in + rg_ * hn);
            float ho = w[F_H + row * 256 + col];
            float hv = (1.f - z) * nn + z * ho;
            w[F_H + row * 256 + col] = hv;
            if (!FINAL) {
                ushort_t hb = f2b(hv);
                wb[UB_H2 + row * 512 + col] = hb;
                wb[UB_H2 + row * 512 + 256 + col] = f2b(hv - bf2f(hb));
            }
        }
    }

    if (FINAL) {
        // per-graph arrival counter: 16 blocks/graph; last one does readout.
        const int g = rg >> 2;
        __syncthreads();
        if (t == 0) {
            __threadfence();                           // release h writes
            int prev = atomicAdd((int*)(w + F_GCNT) + g, 1);
            donef = (prev == 15);
        }
        __syncthreads();
        if (!donef) return;
        __threadfence();                               // acquire others' h

        const float* hb = w + F_H + g * 256 * 256;
        float s = 0.f;
        for (int n = 0; n < 256; ++n) s += hb[n * 256 + t];
        gl[t] = s;
        __syncthreads();
        float acc1 = w[F_ROB1 + t];
        for (int k = 0; k < 256; ++k) acc1 += gl[k] * w[F_ROW1 + k * 256 + t];
        t1[t] = relu(acc1);
        __syncthreads();
        if (t < 16) {
            float q = w[F_ROB2 + t];
            for (int k = 0; k < 256; ++k) q += t1[k] * w[F_ROW2 + k * 16 + t];
            if (*(const int*)(w + F_FLAG)) ((float*)out)[g * 16 + t] = q;
            else ((__hip_bfloat16*)out)[g * 16 + t] = __float2bfloat16(q);
        }
    }
}

extern "C" void kernel_launch(void* const* d_in, const int* in_sizes, int n_in,
                              void* d_out, int out_size, void* d_ws, size_t ws_size,
                              hipStream_t stream) {
    float* w = (float*)d_ws;
    ushort_t* wb = (ushort_t*)d_ws;

    static const int dictSz[18]  = {65536,262144,16384,256,65536,256,131072,256,65536,256,
                                    196608,196608,768,768,65536,256,4096,16};
    static const int alphaSz[18] = {262144,196608,196608,768,768,131072,65536,256,256,
                                    65536,16384,65536,256,256,65536,4096,256,16};
    static const int alphaPos[18] = {9,0,10,12,11,13,5,7,6,8,2,1,4,3,14,16,15,17};
    bool dictOK = true, alphaOK = true;
    for (int i = 0; i < 18 && i < n_in; ++i) {
        if (in_sizes[i] != dictSz[i])  dictOK = false;
        if (in_sizes[i] != alphaSz[i]) alphaOK = false;
    }
    const void* P[18];
    for (int l = 0; l < 18; ++l) P[l] = d_in[(!dictOK && alphaOK) ? alphaPos[l] : l];
    const int* adj = (const int*)P[1];

    convwg_kernel<<<NCONV + 216, 256, 0, stream>>>(
        P[0], P[2], P[3], P[4], P[5], P[6], P[7], P[8], P[9],
        P[10], P[11], P[12], P[13], P[14], P[15], P[16], P[17], w);

    prenet_kernel<<<32, 256, 0, stream>>>(w);

    for (int it = 0; it < 3; ++it) {
        hcat_kernel<<<160, 256, 0, stream>>>(w);
        msg_kernel<<<BN_ROWS, 256, 0, stream>>>(w + F_HCAT, adj, wb + UB_EHAT2);
        if (it < 2)
            gigru_kernel<0><<<64, 256, 0, stream>>>(w, d_out);
        else
            gigru_kernel<1><<<64, 256, 0, stream>>>(w, d_out);
    }
}

// Round 9
// 265.300 us; speedup vs baseline: 1.3290x; 1.1205x over previous
//
#include <hip/hip_runtime.h>
#include <hip/hip_bf16.h>

// B=4, N=256, F=64, H=256, A=16, T=3.  BN=1024 rows.
// bf16 inputs (runtime-verified); adjacency int32.
// GEMMs: bf16 MFMA 16x16x32. Weights are EXACT in bf16 (inputs are bf16).
// Precision: activations h/Ehat stored as split hi/lo bf16 pairs along K,
// weights duplicated along K -> A_hi@B + A_lo@B in one MFMA GEMM (~fp32 acc).
// R1: agg.gi fused via Wg = W2hat.Wih. R2: 311us. R3/R4: megakernel abandoned.
// R5/R6: convwg/prenet/gigru fusion. R7: K-dedup, 64blk, reg-prefetch: 308.9.
// R8: BK=96 + LDS pad + XCD-dedup -> 297.3; gigru still 51.7us x3.
//     DIAGNOSIS: rounds 27->9 gained ~1us; FETCH 12.3->7MB gained 19us ->
//     gigru is per-CU latency-throughput bound (~2.2GB/s/CU) on 64 CUs.
// R9: 4x CU coverage. gigru BM=16: 256 blocks (64rg x 4cg), wave owns
//     gate-aligned frags {w,w+4,w+8} (epilogue stays register-local).
//     hcat BM=32: 320 blocks. K-order unchanged -> bitwise-identical.

typedef unsigned short ushort_t;
typedef short bf8_t __attribute__((ext_vector_type(8)));
typedef float f4_t  __attribute__((ext_vector_type(4)));

#define BN_ROWS 1024

// ---- bf16 regions (USHORT offsets) ----
#define UB_NFB    0         // 65536   NF [1024][64] (exact)
#define UB_PW1T   65536     // 16384   preW1^T [256][64]
#define UB_PW2T   81920     // 65536   preW2^T [256][256]
#define UB_WCATT  147456    // 327680  Wcat^T [1280][256] (dedup: k&255)
#define UB_WGT    475136    // 442368  Wg^T [768][576] = [hi(288)|lo(288)]
#define UB_H2     917504    // 524288  h  [1024][512] hi|lo
#define UB_EHAT2  1441792   // 589824  Ehat [1024][576] = [Eh(288)|El(288)]
// end 2031616 ushorts = 1015808 floats

// ---- fp32 regions (FLOAT offsets) ----
#define F_PREB1   1015808   // 256
#define F_PREB2   1016064   // 256
#define F_BCAT    1016320   // 1280  [msg_b1 | 0 | gru_bhh]
#define F_BIH     1017600   // 768
#define F_ROW1    1018368   // 65536
#define F_ROB1    1083904   // 256
#define F_ROW2    1084160   // 4096
#define F_ROB2    1088256   // 16
#define F_H       1088272   // 262144
#define F_HCAT    1350416   // 1310720 [hi_p | hj | gh]
#define F_FLAG    2661136   // 1 int
#define F_GCNT    2661140   // 4 ints: per-graph readout arrival counters

// ---- convert index space ----
#define CVa 65536     // end NFB
#define CVb 81920     // end PW1T
#define CVc 147456    // end PW2T
#define CVd 475136    // end WCATT (1280*256)
#define CV_TOTAL 547600   // + 72464 fp32 tail
#define NCONV 1070        // convert blocks (2 elems/thread); wg blocks follow

__device__ __forceinline__ float bf2f(ushort_t u) {
    return __uint_as_float(((unsigned int)u) << 16);
}
__device__ __forceinline__ ushort_t f2b(float v) {
    __hip_bfloat16 b = __float2bfloat16(v);
    return *reinterpret_cast<ushort_t*>(&b);
}
__device__ __forceinline__ float relu(float v) { return v < 0.f ? 0.f : v; }  // NaN-propagating
__device__ __forceinline__ float ld(const void* p, int i, int isf32) {
    return isf32 ? ((const float*)p)[i] : bf2f(((const ushort_t*)p)[i]);
}

// detect + convert (blocks [0,NCONV)) + wg (blocks [NCONV,NCONV+216)).
__global__ __launch_bounds__(256) void convwg_kernel(
    const void* nf, const void* preW1, const void* preb1, const void* preW2, const void* preb2,
    const void* msgW1, const void* msgb1, const void* msgW2, const void* msgb2,
    const void* gruWih, const void* gruWhh, const void* grubih, const void* grubhh,
    const void* roW1, const void* rob1, const void* roW2, const void* rob2,
    float* __restrict__ w)
{
    __shared__ float w2s[4 * 256];
    __shared__ int cnt;
    const int t = threadIdx.x;
    ushort_t* wb = (ushort_t*)w;

    // ---- inline detect (redundant per block; 4KB L2-hit scan) ----
    if (t == 0) cnt = 0;
    __syncthreads();
    {
        const ushort_t* nf0 = (const ushort_t*)nf;
        int bad = 0;
        for (int i = 0; i < 8; ++i) {
            ushort_t u = nf0[(t * 8 + i) * 2];
            int ex = (u >> 7) & 0xFF;
            if ((u & 0x7fff) != 0 && (ex < 100 || ex > 140)) bad++;
        }
        atomicAdd(&cnt, bad);
    }
    __syncthreads();
    const int f32 = (cnt > 512) ? 1 : 0;

    if (blockIdx.x == 0) {          // publish flag + zero readout counters
        if (t < 4) ((int*)(w + F_GCNT))[t] = 0;
        if (t == 4) *(int*)(w + F_FLAG) = f32;
    }

    if (blockIdx.x < NCONV) {
        const int e0 = (blockIdx.x * 256 + t) * 2;
#pragma unroll
        for (int u2 = 0; u2 < 2; ++u2) {
            int e = e0 + u2;
            if (e >= CV_TOTAL) break;
            if (e < CVa) {                                    // NF
                wb[UB_NFB + e] = f2b(ld(nf, e, f32));
            } else if (e < CVb) {                             // preW1^T [256][64]
                int i = e - CVa; int n = i >> 6, k = i & 63;
                wb[UB_PW1T + i] = f2b(ld(preW1, k * 256 + n, f32));
            } else if (e < CVc) {                             // preW2^T [256][256]
                int i = e - CVb; int n = i >> 8, k = i & 255;
                wb[UB_PW2T + i] = f2b(ld(preW2, k * 256 + n, f32));
            } else if (e < CVd) {                             // Wcat^T [1280][256]
                int i = e - CVc; int n = i >> 8, k = i & 255;
                float v;
                if (n < 256)      v = ld(msgW1, k * 256 + n, f32);
                else if (n < 512) v = ld(msgW1, (256 + k) * 256 + (n - 256), f32);
                else              v = ld(gruWhh, k * 768 + (n - 512), f32);
                wb[UB_WCATT + i] = f2b(v);
            } else {                                          // fp32 tail
                int f = e - CVd;
                float v;
                if (f < 256)        v = ld(preb1, f, f32);
                else if (f < 512)   v = ld(preb2, f - 256, f32);
                else if (f < 1792) {
                    int c = f - 512;
                    if (c < 256)      v = ld(msgb1, c, f32);
                    else if (c < 512) v = 0.f;
                    else              v = ld(grubhh, c - 512, f32);
                }
                else if (f < 2560)  v = ld(grubih, f - 1792, f32);
                else if (f < 68096) v = ld(roW1, f - 2560, f32);
                else if (f < 68352) v = ld(rob1, f - 68096, f32);
                else if (f < 72448) v = ld(roW2, f - 68352, f32);
                else                v = ld(rob2, f - 72448, f32);
                w[F_PREB1 + f] = v;
            }
        }
        return;
    }

    // ---- wg path: Wg[k][p] = sum_n W2hat[k][n]*Wih[n][p] -> WgT[p][576] ----
    const int wt = blockIdx.x - NCONV;   // [0,216)
    const int p0 = (wt % 3) * 256;
    const int k0 = (wt / 3) * 4;
    for (int i = t; i < 4 * 256; i += 256) {
        int r = i >> 8, n = i & 255;
        int krow = k0 + r;
        float v;
        if (krow < 256)       v = ld(msgW2, krow * 256 + n, f32);
        else if (krow == 256) v = ld(msgb2, n, f32);
        else                  v = 0.f;
        w2s[i] = v;
    }
    __syncthreads();
    const int p = p0 + t;
    float acc4[4] = {};
    for (int n0 = 0; n0 < 256; n0 += 32) {
        float wv[32];
#pragma unroll
        for (int i = 0; i < 32; ++i)
            wv[i] = ld(gruWih, (n0 + i) * 768 + p, f32);
#pragma unroll
        for (int r = 0; r < 4; ++r) {
            float acc = acc4[r];
#pragma unroll
            for (int q = 0; q < 8; ++q) {
                f4_t w4 = *(const f4_t*)&w2s[r * 256 + n0 + q * 4];
                acc += w4[0] * wv[q * 4 + 0] + w4[1] * wv[q * 4 + 1]
                     + w4[2] * wv[q * 4 + 2] + w4[3] * wv[q * 4 + 3];
            }
            acc4[r] = acc;
        }
    }
#pragma unroll
    for (int r = 0; r < 4; ++r) {
        int krow = k0 + r;
        ushort_t hi = f2b(acc4[r]);
        ushort_t lo = f2b(acc4[r] - bf2f(hi));
        wb[UB_WGT + p * 576 + krow] = hi;
        wb[UB_WGT + p * 576 + 288 + krow] = lo;
    }
}

// Fused pre-net: X = relu(NF@preW1+b1) (in LDS), h = X@preW2+b2.
// 32 blocks x 32 rows; wave w: rows (w&1)*16, cols (w>>1)*128 (8 n-frags).
__global__ __launch_bounds__(256) void prenet_kernel(float* __restrict__ w)
{
    __shared__ ushort_t As[32 * 64];    // NF tile      4KB
    __shared__ ushort_t Xs[32 * 256];   // X tile      16KB
    __shared__ ushort_t Bs[256 * 32];   // weight slab 16KB
    ushort_t* wb = (ushort_t*)w;
    const int t = threadIdx.x;
    const int wave = t >> 6, lane = t & 63;
    const int ln = lane & 15, quad = lane >> 4;
    const int wr = (wave & 1) * 16, wc = (wave >> 1) * 128;
    const int rbase = blockIdx.x * 32;
    const int srow = t >> 2, skc = (t & 3) << 3;

    // stage NF tile [32][64]: 1 bf8 per thread
    {
        int row = t >> 3, kc = (t & 7) << 3;
        *(bf8_t*)(&As[row * 64 + kc]) =
            *(const bf8_t*)(&wb[UB_NFB + (rbase + row) * 64 + kc]);
    }

    f4_t acc[8] = {};
    // phase A: X = relu(NF @ PW1T + b1), K=64
    for (int k0 = 0; k0 < 64; k0 += 32) {
        __syncthreads();
#pragma unroll
        for (int rr = 0; rr < 4; ++rr) {
            int n = srow + 64 * rr;
            *(bf8_t*)(&Bs[n * 32 + skc]) =
                *(const bf8_t*)(&wb[UB_PW1T + n * 64 + k0 + skc]);
        }
        __syncthreads();
        bf8_t af = *(const bf8_t*)(&As[(wr + ln) * 64 + k0 + quad * 8]);
#pragma unroll
        for (int n = 0; n < 8; ++n) {
            bf8_t bfr = *(const bf8_t*)(&Bs[(wc + n * 16 + ln) * 32 + quad * 8]);
            acc[n] = __builtin_amdgcn_mfma_f32_16x16x32_bf16(af, bfr, acc[n], 0, 0, 0);
        }
    }
    __syncthreads();
#pragma unroll
    for (int n = 0; n < 8; ++n) {
        int col = wc + n * 16 + ln;
        float bb = w[F_PREB1 + col];
#pragma unroll
        for (int r = 0; r < 4; ++r) {
            int row = wr + quad * 4 + r;
            Xs[row * 256 + col] = f2b(relu(acc[n][r] + bb));
        }
        acc[n] = (f4_t){0.f, 0.f, 0.f, 0.f};
    }
    __syncthreads();

    // phase B: h = X @ PW2T + b2, K=256
    for (int k0 = 0; k0 < 256; k0 += 32) {
        __syncthreads();
#pragma unroll
        for (int rr = 0; rr < 4; ++rr) {
            int n = srow + 64 * rr;
            *(bf8_t*)(&Bs[n * 32 + skc]) =
                *(const bf8_t*)(&wb[UB_PW2T + n * 256 + k0 + skc]);
        }
        __syncthreads();
        bf8_t af = *(const bf8_t*)(&Xs[(wr + ln) * 256 + k0 + quad * 8]);
#pragma unroll
        for (int n = 0; n < 8; ++n) {
            bf8_t bfr = *(const bf8_t*)(&Bs[(wc + n * 16 + ln) * 32 + quad * 8]);
            acc[n] = __builtin_amdgcn_mfma_f32_16x16x32_bf16(af, bfr, acc[n], 0, 0, 0);
        }
    }
#pragma unroll
    for (int n = 0; n < 8; ++n) {
        int col = wc + n * 16 + ln;
        float bb = w[F_PREB2 + col];
#pragma unroll
        for (int r = 0; r < 4; ++r) {
            int grow = rbase + wr + quad * 4 + r;
            float v = acc[n][r] + bb;
            w[F_H + grow * 256 + col] = v;
            ushort_t hi = f2b(v);
            wb[UB_H2 + grow * 512 + col] = hi;
            wb[UB_H2 + grow * 512 + 256 + col] = f2b(v - bf2f(hi));
        }
    }
}

// hcat GEMM: C[1024,1280] = H2[1024,512] @ WcatT[1280,256 dedup]^T + bias.
// 32x128 tiles, 320 blocks (bm-inner). BK=64 (8 rounds), LDS stride 104u.
// Register-prefetch distance 1. Wave = 16 rows x 64 cols (1 m x 4 n frags).
#define HLD 104
__global__ __launch_bounds__(256) void hcat_kernel(float* __restrict__ w)
{
    __shared__ ushort_t As[32 * HLD];    // 6.6KB
    __shared__ ushort_t Bs[128 * HLD];   // 26.6KB
    ushort_t* wb = (ushort_t*)w;
    const ushort_t* A  = wb + UB_H2;
    const ushort_t* Bt = wb + UB_WCATT;
    const int t = threadIdx.x;
    const int wave = t >> 6, lane = t & 63;
    const int ln = lane & 15, quad = lane >> 4;
    const int bm = (blockIdx.x & 31) * 32, bn = (blockIdx.x >> 5) * 128;
    const int wm = (wave >> 1) * 16, wn = (wave & 1) * 64;

    // staging: A 32 rows x 64u = 256 chunks (1/thread); B 128x64u (4/thread)
    const int arow = t >> 3, akc = (t & 7) << 3;
    const int agoff = (bm + arow) * 512 + akc;
    const int aloff = arow * HLD + akc;
    int bgoff[4], bloff[4];
#pragma unroll
    for (int i = 0; i < 4; ++i) {
        int slot = i * 256 + t;
        int brow = slot >> 3, bkc = (slot & 7) << 3;
        bgoff[i] = (bn + brow) * 256 + bkc;
        bloff[i] = brow * HLD + bkc;
    }

    f4_t acc[4] = {};
    bf8_t ra, rb[4];

    ra = *(const bf8_t*)(&A[agoff]);
#pragma unroll
    for (int i = 0; i < 4; ++i)
        rb[i] = *(const bf8_t*)(&Bt[bgoff[i]]);

    for (int ks = 0; ks < 8; ++ks) {
        __syncthreads();
        *(bf8_t*)(&As[aloff]) = ra;
#pragma unroll
        for (int i = 0; i < 4; ++i)
            *(bf8_t*)(&Bs[bloff[i]]) = rb[i];
        __syncthreads();
        if (ks < 7) {
            int k0 = (ks + 1) * 64;
            int kb = k0 & 255;
            ra = *(const bf8_t*)(&A[agoff + k0]);
#pragma unroll
            for (int i = 0; i < 4; ++i)
                rb[i] = *(const bf8_t*)(&Bt[bgoff[i] + kb]);
        }
#pragma unroll
        for (int kk = 0; kk < 2; ++kk) {
            bf8_t af = *(const bf8_t*)(&As[(wm + ln) * HLD + kk * 32 + quad * 8]);
#pragma unroll
            for (int ni = 0; ni < 4; ++ni) {
                bf8_t bfr = *(const bf8_t*)(&Bs[(wn + ni * 16 + ln) * HLD + kk * 32 + quad * 8]);
                acc[ni] = __builtin_amdgcn_mfma_f32_16x16x32_bf16(af, bfr, acc[ni], 0, 0, 0);
            }
        }
    }

#pragma unroll
    for (int ni = 0; ni < 4; ++ni) {
        int col = bn + wn + ni * 16 + ln;
        float bb = w[F_BCAT + col];
#pragma unroll
        for (int r = 0; r < 4; ++r) {
            int row = bm + wm + quad * 4 + r;
            w[F_HCAT + row * 1280 + col] = acc[ni][r] + bb;
        }
    }
}

// Ehat[row] (width 576): [ sum relu(hi_p+hj) hi (256) | deg | 0 | lo (256) | 0 ]
__global__ __launch_bounds__(256) void msg_kernel(
    const float* __restrict__ hcat,   // [1024][1280]: [hi_p | hj | gh]
    const int*   __restrict__ adj,    // [1024][256]
    ushort_t* __restrict__ ehat)      // [1024][576]
{
    const int row = blockIdx.x;
    const int t = threadIdx.x;
    __shared__ int ej[256];
    __shared__ int ecnt;
    if (t == 0) ecnt = 0;
    __syncthreads();
    if (adj[row * 256 + t]) { int p = atomicAdd(&ecnt, 1); ej[p] = t; }
    const float hi = hcat[row * 1280 + t];
    const float* hjb = hcat + (row >> 8) * 256 * 1280 + 256;
    __syncthreads();
    const int ne = ecnt;
    float acc = 0.f;
#pragma unroll 4
    for (int p = 0; p < ne; ++p) {
        int j = ej[p];
        acc += relu(hi + hjb[j * 1280 + t]);
    }
    ushort_t h16 = f2b(acc);
    ushort_t l16 = f2b(acc - bf2f(h16));
    ushort_t* er = ehat + row * 576;
    er[t] = h16;
    er[288 + t] = l16;
    if (t < 32) {
        er[256 + t] = f2b(t == 0 ? (float)ne : 0.f);  // deg exact (<=256)
        er[544 + t] = 0;
    }
}

// Fused gi-GEMM + GRU.  256 blocks = 64 rowgroups(16 rows) x 4 colgroups.
//   xcd=bid&7; cg=xcd&3; rg=(bid>>3)+32*(xcd>>2): B panel single-XCD,
//   A 4-way XCD-replicated (L3-absorbed). All 256 CUs active.
// gi = Ehat @ Wg + bih; logical K=864 = [Eh@hi | El@hi | Eh@lo] via per-round
// uniform source remap (576/288 both multiples of BK=96). BK=96, 9 rounds,
// LDS stride 104u. Wave w owns gate-aligned frags {w, w+4, w+8} -> each
// thread holds ir/iz/in for col cg*64+w*16+ln; GRU in epilogue.
// FINAL: last block per graph (arrival counter to 64) does readout.
#define GLD 104
template<int FINAL>
__global__ __launch_bounds__(256) void gigru_kernel(float* __restrict__ w,
                                                    void* __restrict__ out)
{
    __shared__ ushort_t As[16 * GLD];    // 3.3KB
    __shared__ ushort_t Bs[192 * GLD];   // 40KB
    __shared__ float gl[256];
    __shared__ float t1[256];
    __shared__ int donef;
    ushort_t* wb = (ushort_t*)w;
    const int t = threadIdx.x;
    const int wave = t >> 6, lane = t & 63;
    const int ln = lane & 15, quad = lane >> 4;
    const int xcd = blockIdx.x & 7;
    const int cg = xcd & 3;
    const int rg = (blockIdx.x >> 3) + 32 * (xcd >> 2);   // 0..63
    const int rbase = rg * 16;

    // staging: A 16 rows x 96u = 192 chunks (threads t<192); B 192x96u (9/thread)
    const int aval = (t < 192);
    const int arow = t / 12, akc = (t % 12) * 8;
    const int agoff = (rbase + arow) * 576 + akc;
    const int aloff = arow * GLD + akc;
    int bgoff[9], bloff[9];
#pragma unroll
    for (int i = 0; i < 9; ++i) {
        int slot = i * 256 + t;
        int brow = slot / 12, bkc = (slot % 12) * 8;
        int wrow = (brow >> 6) * 256 + cg * 64 + (brow & 63);
        bgoff[i] = wrow * 576 + bkc;
        bloff[i] = brow * GLD + bkc;
    }
    const ushort_t* Ehp = wb + UB_EHAT2;
    const ushort_t* Bp  = wb + UB_WGT;

    f4_t acc[3] = {};
    bf8_t ra, rb[9];

    // k remaps (uniform per round; 576 and 288 are multiples of 96):
    //   A: k<576 -> k, else k-576 (Eh reused).  B: k<288 -> k, else k-288.
    if (aval) ra = *(const bf8_t*)(&Ehp[agoff]);
#pragma unroll
    for (int i = 0; i < 9; ++i)
        rb[i] = *(const bf8_t*)(&Bp[bgoff[i]]);

    for (int ks = 0; ks < 9; ++ks) {
        __syncthreads();
        if (aval) *(bf8_t*)(&As[aloff]) = ra;
#pragma unroll
        for (int i = 0; i < 9; ++i)
            *(bf8_t*)(&Bs[bloff[i]]) = rb[i];
        __syncthreads();
        if (ks < 8) {
            int k0 = (ks + 1) * 96;
            int ka = (k0 < 576) ? k0 : k0 - 576;
            int kb = (k0 < 288) ? k0 : k0 - 288;
            if (aval) ra = *(const bf8_t*)(&Ehp[agoff + ka]);
#pragma unroll
            for (int i = 0; i < 9; ++i)
                rb[i] = *(const bf8_t*)(&Bp[bgoff[i] + kb]);
        }
#pragma unroll
        for (int kk = 0; kk < 3; ++kk) {
            bf8_t af = *(const bf8_t*)(&As[ln * GLD + kk * 32 + quad * 8]);
#pragma unroll
            for (int n = 0; n < 3; ++n) {
                int fn = wave + n * 4;           // gate n, sub = wave
                bf8_t bfr = *(const bf8_t*)(&Bs[(fn * 16 + ln) * GLD + kk * 32 + quad * 8]);
                acc[n] = __builtin_amdgcn_mfma_f32_16x16x32_bf16(af, bfr, acc[n], 0, 0, 0);
            }
        }
    }

    // GRU epilogue: acc[0]=ir, acc[1]=iz, acc[2]=in for col below.
    {
        const int col = cg * 64 + wave * 16 + ln;
        float bi_r = w[F_BIH + col];
        float bi_z = w[F_BIH + 256 + col];
        float bi_n = w[F_BIH + 512 + col];
#pragma unroll
        for (int r = 0; r < 4; ++r) {
            int row = rbase + quad * 4 + r;
            float ir = acc[0][r] + bi_r;
            float iz = acc[1][r] + bi_z;
            float in = acc[2][r] + bi_n;
            const float* ghr = w + F_HCAT + row * 1280 + 512;
            float hr = ghr[col], hz = ghr[256 + col], hn = ghr[512 + col];
            float rg_ = 1.f / (1.f + __expf(-(ir + hr)));
            float z   = 1.f / (1.f + __expf(-(iz + hz)));
            float nn  = tanhf(in + rg_ * hn);
            float ho = w[F_H + row * 256 + col];
            float hv = (1.f - z) * nn + z * ho;
            w[F_H + row * 256 + col] = hv;
            if (!FINAL) {
                ushort_t hb = f2b(hv);
                wb[UB_H2 + row * 512 + col] = hb;
                wb[UB_H2 + row * 512 + 256 + col] = f2b(hv - bf2f(hb));
            }
        }
    }

    if (FINAL) {
        // per-graph arrival counter: 64 blocks/graph; last one does readout.
        const int g = rg >> 4;
        __syncthreads();
        if (t == 0) {
            __threadfence();                           // release h writes
            int prev = atomicAdd((int*)(w + F_GCNT) + g, 1);
            donef = (prev == 63);
        }
        __syncthreads();
        if (!donef) return;
        __threadfence();                               // acquire others' h

        const float* hb = w + F_H + g * 256 * 256;
        float s = 0.f;
        for (int n = 0; n < 256; ++n) s += hb[n * 256 + t];
        gl[t] = s;
        __syncthreads();
        float acc1 = w[F_ROB1 + t];
        for (int k = 0; k < 256; ++k) acc1 += gl[k] * w[F_ROW1 + k * 256 + t];
        t1[t] = relu(acc1);
        __syncthreads();
        if (t < 16) {
            float q = w[F_ROB2 + t];
            for (int k = 0; k < 256; ++k) q += t1[k] * w[F_ROW2 + k * 16 + t];
            if (*(const int*)(w + F_FLAG)) ((float*)out)[g * 16 + t] = q;
            else ((__hip_bfloat16*)out)[g * 16 + t] = __float2bfloat16(q);
        }
    }
}

extern "C" void kernel_launch(void* const* d_in, const int* in_sizes, int n_in,
                              void* d_out, int out_size, void* d_ws, size_t ws_size,
                              hipStream_t stream) {
    float* w = (float*)d_ws;
    ushort_t* wb = (ushort_t*)d_ws;

    static const int dictSz[18]  = {65536,262144,16384,256,65536,256,131072,256,65536,256,
                                    196608,196608,768,768,65536,256,4096,16};
    static const int alphaSz[18] = {262144,196608,196608,768,768,131072,65536,256,256,
                                    65536,16384,65536,256,256,65536,4096,256,16};
    static const int alphaPos[18] = {9,0,10,12,11,13,5,7,6,8,2,1,4,3,14,16,15,17};
    bool dictOK = true, alphaOK = true;
    for (int i = 0; i < 18 && i < n_in; ++i) {
        if (in_sizes[i] != dictSz[i])  dictOK = false;
        if (in_sizes[i] != alphaSz[i]) alphaOK = false;
    }
    const void* P[18];
    for (int l = 0; l < 18; ++l) P[l] = d_in[(!dictOK && alphaOK) ? alphaPos[l] : l];
    const int* adj = (const int*)P[1];

    convwg_kernel<<<NCONV + 216, 256, 0, stream>>>(
        P[0], P[2], P[3], P[4], P[5], P[6], P[7], P[8], P[9],
        P[10], P[11], P[12], P[13], P[14], P[15], P[16], P[17], w);

    prenet_kernel<<<32, 256, 0, stream>>>(w);

    for (int it = 0; it < 3; ++it) {
        hcat_kernel<<<320, 256, 0, stream>>>(w);
        msg_kernel<<<BN_ROWS, 256, 0, stream>>>(w + F_HCAT, adj, wb + UB_EHAT2);
        if (it < 2)
            gigru_kernel<0><<<256, 256, 0, stream>>>(w, d_out);
        else
            gigru_kernel<1><<<256, 256, 0, stream>>>(w, d_out);
    }
}

// Round 10
// 262.715 us; speedup vs baseline: 1.3421x; 1.0098x over previous
//
#include <hip/hip_runtime.h>
#include <hip/hip_bf16.h>

// B=4, N=256, F=64, H=256, A=16, T=3.  BN=1024 rows.
// bf16 inputs (runtime-verified); adjacency int32.
// GEMMs: bf16 MFMA 16x16x32. Weights are EXACT in bf16 (inputs are bf16).
// Precision: activations h/Ehat stored as split hi/lo bf16 pairs along K,
// weights duplicated along K -> A_hi@B + A_lo@B in one MFMA GEMM (~fp32 acc).
// R1: agg.gi fused via Wg = W2hat.Wih. R2: 311us. R3/R4: megakernel abandoned.
// R5-R8: fusion + K-dedup + LDS pad + XCD maps -> 297us.
// R9: gigru 256 blocks -> 265us; gigru 44us INVARIANT across k-loop changes
//     (R7 53 / R8 51.7 / R9 44) -> cost lives in the GRU epilogue's scattered
//     fp32 gh reads (3.1MB, HBM-cold after harness's 268MB poison fill).
// R10: gh-fusion. gigru gains phase 2: gh = h@Whh (A=H2 16x512, B=WCATT rows
//     512..1280, BK=64, same ascending-k MFMA chain as hcat used -> bitwise
//     identical); bhh added in epilogue. Epilogue now register-local.
//     hcat shrinks to N=512 ([hi_p|hj], 128 blocks); msg stride 1280->512.

typedef unsigned short ushort_t;
typedef short bf8_t __attribute__((ext_vector_type(8)));
typedef float f4_t  __attribute__((ext_vector_type(4)));

#define BN_ROWS 1024

// ---- bf16 regions (USHORT offsets) ----
#define UB_NFB    0         // 65536   NF [1024][64] (exact)
#define UB_PW1T   65536     // 16384   preW1^T [256][64]
#define UB_PW2T   81920     // 65536   preW2^T [256][256]
#define UB_WCATT  147456    // 327680  Wcat^T [1280][256] (dedup: k&255)
#define UB_WGT    475136    // 442368  Wg^T [768][576] = [hi(288)|lo(288)]
#define UB_H2     917504    // 524288  h  [1024][512] hi|lo
#define UB_EHAT2  1441792   // 589824  Ehat [1024][576] = [Eh(288)|El(288)]
// end 2031616 ushorts = 1015808 floats

// ---- fp32 regions (FLOAT offsets) ----
#define F_PREB1   1015808   // 256
#define F_PREB2   1016064   // 256
#define F_BCAT    1016320   // 1280  [msg_b1 | 0 | gru_bhh]
#define F_BIH     1017600   // 768
#define F_ROW1    1018368   // 65536
#define F_ROB1    1083904   // 256
#define F_ROW2    1084160   // 4096
#define F_ROB2    1088256   // 16
#define F_H       1088272   // 262144
#define F_HCAT    1350416   // 524288 [hi_p | hj]  (gh no longer materialized)
#define F_FLAG    2661136   // 1 int
#define F_GCNT    2661140   // 4 ints: per-graph readout arrival counters

// ---- convert index space ----
#define CVa 65536     // end NFB
#define CVb 81920     // end PW1T
#define CVc 147456    // end PW2T
#define CVd 475136    // end WCATT (1280*256)
#define CV_TOTAL 547600   // + 72464 fp32 tail
#define NCONV 1070        // convert blocks (2 elems/thread); wg blocks follow

__device__ __forceinline__ float bf2f(ushort_t u) {
    return __uint_as_float(((unsigned int)u) << 16);
}
__device__ __forceinline__ ushort_t f2b(float v) {
    __hip_bfloat16 b = __float2bfloat16(v);
    return *reinterpret_cast<ushort_t*>(&b);
}
__device__ __forceinline__ float relu(float v) { return v < 0.f ? 0.f : v; }  // NaN-propagating
__device__ __forceinline__ float ld(const void* p, int i, int isf32) {
    return isf32 ? ((const float*)p)[i] : bf2f(((const ushort_t*)p)[i]);
}

// detect + convert (blocks [0,NCONV)) + wg (blocks [NCONV,NCONV+216)).
__global__ __launch_bounds__(256) void convwg_kernel(
    const void* nf, const void* preW1, const void* preb1, const void* preW2, const void* preb2,
    const void* msgW1, const void* msgb1, const void* msgW2, const void* msgb2,
    const void* gruWih, const void* gruWhh, const void* grubih, const void* grubhh,
    const void* roW1, const void* rob1, const void* roW2, const void* rob2,
    float* __restrict__ w)
{
    __shared__ float w2s[4 * 256];
    __shared__ int cnt;
    const int t = threadIdx.x;
    ushort_t* wb = (ushort_t*)w;

    // ---- inline detect (redundant per block; 4KB L2-hit scan) ----
    if (t == 0) cnt = 0;
    __syncthreads();
    {
        const ushort_t* nf0 = (const ushort_t*)nf;
        int bad = 0;
        for (int i = 0; i < 8; ++i) {
            ushort_t u = nf0[(t * 8 + i) * 2];
            int ex = (u >> 7) & 0xFF;
            if ((u & 0x7fff) != 0 && (ex < 100 || ex > 140)) bad++;
        }
        atomicAdd(&cnt, bad);
    }
    __syncthreads();
    const int f32 = (cnt > 512) ? 1 : 0;

    if (blockIdx.x == 0) {          // publish flag + zero readout counters
        if (t < 4) ((int*)(w + F_GCNT))[t] = 0;
        if (t == 4) *(int*)(w + F_FLAG) = f32;
    }

    if (blockIdx.x < NCONV) {
        const int e0 = (blockIdx.x * 256 + t) * 2;
#pragma unroll
        for (int u2 = 0; u2 < 2; ++u2) {
            int e = e0 + u2;
            if (e >= CV_TOTAL) break;
            if (e < CVa) {                                    // NF
                wb[UB_NFB + e] = f2b(ld(nf, e, f32));
            } else if (e < CVb) {                             // preW1^T [256][64]
                int i = e - CVa; int n = i >> 6, k = i & 63;
                wb[UB_PW1T + i] = f2b(ld(preW1, k * 256 + n, f32));
            } else if (e < CVc) {                             // preW2^T [256][256]
                int i = e - CVb; int n = i >> 8, k = i & 255;
                wb[UB_PW2T + i] = f2b(ld(preW2, k * 256 + n, f32));
            } else if (e < CVd) {                             // Wcat^T [1280][256]
                int i = e - CVc; int n = i >> 8, k = i & 255;
                float v;
                if (n < 256)      v = ld(msgW1, k * 256 + n, f32);
                else if (n < 512) v = ld(msgW1, (256 + k) * 256 + (n - 256), f32);
                else              v = ld(gruWhh, k * 768 + (n - 512), f32);
                wb[UB_WCATT + i] = f2b(v);
            } else {                                          // fp32 tail
                int f = e - CVd;
                float v;
                if (f < 256)        v = ld(preb1, f, f32);
                else if (f < 512)   v = ld(preb2, f - 256, f32);
                else if (f < 1792) {
                    int c = f - 512;
                    if (c < 256)      v = ld(msgb1, c, f32);
                    else if (c < 512) v = 0.f;
                    else              v = ld(grubhh, c - 512, f32);
                }
                else if (f < 2560)  v = ld(grubih, f - 1792, f32);
                else if (f < 68096) v = ld(roW1, f - 2560, f32);
                else if (f < 68352) v = ld(rob1, f - 68096, f32);
                else if (f < 72448) v = ld(roW2, f - 68352, f32);
                else                v = ld(rob2, f - 72448, f32);
                w[F_PREB1 + f] = v;
            }
        }
        return;
    }

    // ---- wg path: Wg[k][p] = sum_n W2hat[k][n]*Wih[n][p] -> WgT[p][576] ----
    const int wt = blockIdx.x - NCONV;   // [0,216)
    const int p0 = (wt % 3) * 256;
    const int k0 = (wt / 3) * 4;
    for (int i = t; i < 4 * 256; i += 256) {
        int r = i >> 8, n = i & 255;
        int krow = k0 + r;
        float v;
        if (krow < 256)       v = ld(msgW2, krow * 256 + n, f32);
        else if (krow == 256) v = ld(msgb2, n, f32);
        else                  v = 0.f;
        w2s[i] = v;
    }
    __syncthreads();
    const int p = p0 + t;
    float acc4[4] = {};
    for (int n0 = 0; n0 < 256; n0 += 32) {
        float wv[32];
#pragma unroll
        for (int i = 0; i < 32; ++i)
            wv[i] = ld(gruWih, (n0 + i) * 768 + p, f32);
#pragma unroll
        for (int r = 0; r < 4; ++r) {
            float acc = acc4[r];
#pragma unroll
            for (int q = 0; q < 8; ++q) {
                f4_t w4 = *(const f4_t*)&w2s[r * 256 + n0 + q * 4];
                acc += w4[0] * wv[q * 4 + 0] + w4[1] * wv[q * 4 + 1]
                     + w4[2] * wv[q * 4 + 2] + w4[3] * wv[q * 4 + 3];
            }
            acc4[r] = acc;
        }
    }
#pragma unroll
    for (int r = 0; r < 4; ++r) {
        int krow = k0 + r;
        ushort_t hi = f2b(acc4[r]);
        ushort_t lo = f2b(acc4[r] - bf2f(hi));
        wb[UB_WGT + p * 576 + krow] = hi;
        wb[UB_WGT + p * 576 + 288 + krow] = lo;
    }
}

// Fused pre-net: X = relu(NF@preW1+b1) (in LDS), h = X@preW2+b2.
// 32 blocks x 32 rows; wave w: rows (w&1)*16, cols (w>>1)*128 (8 n-frags).
__global__ __launch_bounds__(256) void prenet_kernel(float* __restrict__ w)
{
    __shared__ ushort_t As[32 * 64];    // NF tile      4KB
    __shared__ ushort_t Xs[32 * 256];   // X tile      16KB
    __shared__ ushort_t Bs[256 * 32];   // weight slab 16KB
    ushort_t* wb = (ushort_t*)w;
    const int t = threadIdx.x;
    const int wave = t >> 6, lane = t & 63;
    const int ln = lane & 15, quad = lane >> 4;
    const int wr = (wave & 1) * 16, wc = (wave >> 1) * 128;
    const int rbase = blockIdx.x * 32;
    const int srow = t >> 2, skc = (t & 3) << 3;

    // stage NF tile [32][64]: 1 bf8 per thread
    {
        int row = t >> 3, kc = (t & 7) << 3;
        *(bf8_t*)(&As[row * 64 + kc]) =
            *(const bf8_t*)(&wb[UB_NFB + (rbase + row) * 64 + kc]);
    }

    f4_t acc[8] = {};
    // phase A: X = relu(NF @ PW1T + b1), K=64
    for (int k0 = 0; k0 < 64; k0 += 32) {
        __syncthreads();
#pragma unroll
        for (int rr = 0; rr < 4; ++rr) {
            int n = srow + 64 * rr;
            *(bf8_t*)(&Bs[n * 32 + skc]) =
                *(const bf8_t*)(&wb[UB_PW1T + n * 64 + k0 + skc]);
        }
        __syncthreads();
        bf8_t af = *(const bf8_t*)(&As[(wr + ln) * 64 + k0 + quad * 8]);
#pragma unroll
        for (int n = 0; n < 8; ++n) {
            bf8_t bfr = *(const bf8_t*)(&Bs[(wc + n * 16 + ln) * 32 + quad * 8]);
            acc[n] = __builtin_amdgcn_mfma_f32_16x16x32_bf16(af, bfr, acc[n], 0, 0, 0);
        }
    }
    __syncthreads();
#pragma unroll
    for (int n = 0; n < 8; ++n) {
        int col = wc + n * 16 + ln;
        float bb = w[F_PREB1 + col];
#pragma unroll
        for (int r = 0; r < 4; ++r) {
            int row = wr + quad * 4 + r;
            Xs[row * 256 + col] = f2b(relu(acc[n][r] + bb));
        }
        acc[n] = (f4_t){0.f, 0.f, 0.f, 0.f};
    }
    __syncthreads();

    // phase B: h = X @ PW2T + b2, K=256
    for (int k0 = 0; k0 < 256; k0 += 32) {
        __syncthreads();
#pragma unroll
        for (int rr = 0; rr < 4; ++rr) {
            int n = srow + 64 * rr;
            *(bf8_t*)(&Bs[n * 32 + skc]) =
                *(const bf8_t*)(&wb[UB_PW2T + n * 256 + k0 + skc]);
        }
        __syncthreads();
        bf8_t af = *(const bf8_t*)(&Xs[(wr + ln) * 256 + k0 + quad * 8]);
#pragma unroll
        for (int n = 0; n < 8; ++n) {
            bf8_t bfr = *(const bf8_t*)(&Bs[(wc + n * 16 + ln) * 32 + quad * 8]);
            acc[n] = __builtin_amdgcn_mfma_f32_16x16x32_bf16(af, bfr, acc[n], 0, 0, 0);
        }
    }
#pragma unroll
    for (int n = 0; n < 8; ++n) {
        int col = wc + n * 16 + ln;
        float bb = w[F_PREB2 + col];
#pragma unroll
        for (int r = 0; r < 4; ++r) {
            int grow = rbase + wr + quad * 4 + r;
            float v = acc[n][r] + bb;
            w[F_H + grow * 256 + col] = v;
            ushort_t hi = f2b(v);
            wb[UB_H2 + grow * 512 + col] = hi;
            wb[UB_H2 + grow * 512 + 256 + col] = f2b(v - bf2f(hi));
        }
    }
}

// hcat GEMM: C[1024,512] = H2[1024,512] @ WcatT[0..512]^T + bias ([hi_p|hj]).
// 32x128 tiles, 128 blocks (bm-inner). BK=64 (8 rounds), LDS stride 104u.
// Register-prefetch distance 1. Wave = 16 rows x 64 cols (1 m x 4 n frags).
#define HLD 104
__global__ __launch_bounds__(256) void hcat_kernel(float* __restrict__ w)
{
    __shared__ ushort_t As[32 * HLD];    // 6.6KB
    __shared__ ushort_t Bs[128 * HLD];   // 26.6KB
    ushort_t* wb = (ushort_t*)w;
    const ushort_t* A  = wb + UB_H2;
    const ushort_t* Bt = wb + UB_WCATT;
    const int t = threadIdx.x;
    const int wave = t >> 6, lane = t & 63;
    const int ln = lane & 15, quad = lane >> 4;
    const int bm = (blockIdx.x & 31) * 32, bn = (blockIdx.x >> 5) * 128;
    const int wm = (wave >> 1) * 16, wn = (wave & 1) * 64;

    // staging: A 32 rows x 64u = 256 chunks (1/thread); B 128x64u (4/thread)
    const int arow = t >> 3, akc = (t & 7) << 3;
    const int agoff = (bm + arow) * 512 + akc;
    const int aloff = arow * HLD + akc;
    int bgoff[4], bloff[4];
#pragma unroll
    for (int i = 0; i < 4; ++i) {
        int slot = i * 256 + t;
        int brow = slot >> 3, bkc = (slot & 7) << 3;
        bgoff[i] = (bn + brow) * 256 + bkc;
        bloff[i] = brow * HLD + bkc;
    }

    f4_t acc[4] = {};
    bf8_t ra, rb[4];

    ra = *(const bf8_t*)(&A[agoff]);
#pragma unroll
    for (int i = 0; i < 4; ++i)
        rb[i] = *(const bf8_t*)(&Bt[bgoff[i]]);

    for (int ks = 0; ks < 8; ++ks) {
        __syncthreads();
        *(bf8_t*)(&As[aloff]) = ra;
#pragma unroll
        for (int i = 0; i < 4; ++i)
            *(bf8_t*)(&Bs[bloff[i]]) = rb[i];
        __syncthreads();
        if (ks < 7) {
            int k0 = (ks + 1) * 64;
            int kb = k0 & 255;
            ra = *(const bf8_t*)(&A[agoff + k0]);
#pragma unroll
            for (int i = 0; i < 4; ++i)
                rb[i] = *(const bf8_t*)(&Bt[bgoff[i] + kb]);
        }
#pragma unroll
        for (int kk = 0; kk < 2; ++kk) {
            bf8_t af = *(const bf8_t*)(&As[(wm + ln) * HLD + kk * 32 + quad * 8]);
#pragma unroll
            for (int ni = 0; ni < 4; ++ni) {
                bf8_t bfr = *(const bf8_t*)(&Bs[(wn + ni * 16 + ln) * HLD + kk * 32 + quad * 8]);
                acc[ni] = __builtin_amdgcn_mfma_f32_16x16x32_bf16(af, bfr, acc[ni], 0, 0, 0);
            }
        }
    }

#pragma unroll
    for (int ni = 0; ni < 4; ++ni) {
        int col = bn + wn + ni * 16 + ln;
        float bb = w[F_BCAT + col];
#pragma unroll
        for (int r = 0; r < 4; ++r) {
            int row = bm + wm + quad * 4 + r;
            w[F_HCAT + row * 512 + col] = acc[ni][r] + bb;
        }
    }
}

// Ehat[row] (width 576): [ sum relu(hi_p+hj) hi (256) | deg | 0 | lo (256) | 0 ]
__global__ __launch_bounds__(256) void msg_kernel(
    const float* __restrict__ hcat,   // [1024][512]: [hi_p | hj]
    const int*   __restrict__ adj,    // [1024][256]
    ushort_t* __restrict__ ehat)      // [1024][576]
{
    const int row = blockIdx.x;
    const int t = threadIdx.x;
    __shared__ int ej[256];
    __shared__ int ecnt;
    if (t == 0) ecnt = 0;
    __syncthreads();
    if (adj[row * 256 + t]) { int p = atomicAdd(&ecnt, 1); ej[p] = t; }
    const float hi = hcat[row * 512 + t];
    const float* hjb = hcat + (row >> 8) * 256 * 512 + 256;
    __syncthreads();
    const int ne = ecnt;
    float acc = 0.f;
#pragma unroll 4
    for (int p = 0; p < ne; ++p) {
        int j = ej[p];
        acc += relu(hi + hjb[j * 512 + t]);
    }
    ushort_t h16 = f2b(acc);
    ushort_t l16 = f2b(acc - bf2f(h16));
    ushort_t* er = ehat + row * 576;
    er[t] = h16;
    er[288 + t] = l16;
    if (t < 32) {
        er[256 + t] = f2b(t == 0 ? (float)ne : 0.f);  // deg exact (<=256)
        er[544 + t] = 0;
    }
}

// Fused gi-GEMM + gh-GEMM + GRU.  256 blocks = 64 rowgroups(16) x 4 colgroups.
//   xcd=bid&7; cg=xcd&3; rg=(bid>>3)+32*(xcd>>2).
// Phase 1: gi = Ehat @ Wg (logical K=864 via dedup remap), BK=96, 9 rounds.
// Phase 2: gh = h @ Whh (K=512, A=H2, B=WCATT rows 512..1280 dedup k&255),
//   BK=64, 8 rounds -- same ascending-k MFMA chain hcat used -> bitwise-same.
// GRU epilogue fully register-local (bih + bhh biases added here).
// FINAL: last block per graph (arrival counter to 64) does readout.
#define GLD 104
template<int FINAL>
__global__ __launch_bounds__(256) void gigru_kernel(float* __restrict__ w,
                                                    void* __restrict__ out)
{
    __shared__ ushort_t As[16 * GLD];    // 3.3KB
    __shared__ ushort_t Bs[192 * GLD];   // 40KB
    __shared__ float gl[256];
    __shared__ float t1[256];
    __shared__ int donef;
    ushort_t* wb = (ushort_t*)w;
    const int t = threadIdx.x;
    const int wave = t >> 6, lane = t & 63;
    const int ln = lane & 15, quad = lane >> 4;
    const int xcd = blockIdx.x & 7;
    const int cg = xcd & 3;
    const int rg = (blockIdx.x >> 3) + 32 * (xcd >> 2);   // 0..63
    const int rbase = rg * 16;

    // ---------------- phase 1: gi = Ehat @ Wg ----------------
    const int aval = (t < 192);
    const int arow = t / 12, akc = (t % 12) * 8;
    const int agoff = (rbase + arow) * 576 + akc;
    const int aloff = arow * GLD + akc;
    int bgoff[9], bloff[9];
#pragma unroll
    for (int i = 0; i < 9; ++i) {
        int slot = i * 256 + t;
        int brow = slot / 12, bkc = (slot % 12) * 8;
        int wrow = (brow >> 6) * 256 + cg * 64 + (brow & 63);
        bgoff[i] = wrow * 576 + bkc;
        bloff[i] = brow * GLD + bkc;
    }
    const ushort_t* Ehp = wb + UB_EHAT2;
    const ushort_t* Bp  = wb + UB_WGT;

    f4_t acc[3] = {};
    {
        bf8_t ra, rb[9];
        if (aval) ra = *(const bf8_t*)(&Ehp[agoff]);
#pragma unroll
        for (int i = 0; i < 9; ++i)
            rb[i] = *(const bf8_t*)(&Bp[bgoff[i]]);

        for (int ks = 0; ks < 9; ++ks) {
            __syncthreads();
            if (aval) *(bf8_t*)(&As[aloff]) = ra;
#pragma unroll
            for (int i = 0; i < 9; ++i)
                *(bf8_t*)(&Bs[bloff[i]]) = rb[i];
            __syncthreads();
            if (ks < 8) {
                int k0 = (ks + 1) * 96;
                int ka = (k0 < 576) ? k0 : k0 - 576;
                int kb = (k0 < 288) ? k0 : k0 - 288;
                if (aval) ra = *(const bf8_t*)(&Ehp[agoff + ka]);
#pragma unroll
                for (int i = 0; i < 9; ++i)
                    rb[i] = *(const bf8_t*)(&Bp[bgoff[i] + kb]);
            }
#pragma unroll
            for (int kk = 0; kk < 3; ++kk) {
                bf8_t af = *(const bf8_t*)(&As[ln * GLD + kk * 32 + quad * 8]);
#pragma unroll
                for (int n = 0; n < 3; ++n) {
                    int fn = wave + n * 4;           // gate n, sub = wave
                    bf8_t bfr = *(const bf8_t*)(&Bs[(fn * 16 + ln) * GLD + kk * 32 + quad * 8]);
                    acc[n] = __builtin_amdgcn_mfma_f32_16x16x32_bf16(af, bfr, acc[n], 0, 0, 0);
                }
            }
        }
    }

    // ---------------- phase 2: gh = h @ Whh ----------------
    // A = H2 [16][512]; B = WCATT rows 512 + gate*256 + cg*64 + r (dedup k&255)
    const int aval2 = (t < 128);
    const int arow2 = t >> 3, akc2 = (t & 7) << 3;
    const int agoff2 = (rbase + arow2) * 512 + akc2;
    const int aloff2 = arow2 * GLD + akc2;
    int bgoff2[6], bloff2[6];
#pragma unroll
    for (int i = 0; i < 6; ++i) {
        int slot = i * 256 + t;
        int brow = slot >> 3, bkc = (slot & 7) << 3;
        int wrow = 512 + (brow >> 6) * 256 + cg * 64 + (brow & 63);
        bgoff2[i] = wrow * 256 + bkc;
        bloff2[i] = brow * GLD + bkc;
    }
    const ushort_t* Hp = wb + UB_H2;
    const ushort_t* Wp = wb + UB_WCATT;

    f4_t acch[3] = {};
    {
        bf8_t ra, rb[6];
        if (aval2) ra = *(const bf8_t*)(&Hp[agoff2]);
#pragma unroll
        for (int i = 0; i < 6; ++i)
            rb[i] = *(const bf8_t*)(&Wp[bgoff2[i]]);

        for (int ks = 0; ks < 8; ++ks) {
            __syncthreads();
            if (aval2) *(bf8_t*)(&As[aloff2]) = ra;
#pragma unroll
            for (int i = 0; i < 6; ++i)
                *(bf8_t*)(&Bs[bloff2[i]]) = rb[i];
            __syncthreads();
            if (ks < 7) {
                int k0 = (ks + 1) * 64;
                int kb = k0 & 255;
                if (aval2) ra = *(const bf8_t*)(&Hp[agoff2 + k0]);
#pragma unroll
                for (int i = 0; i < 6; ++i)
                    rb[i] = *(const bf8_t*)(&Wp[bgoff2[i] + kb]);
            }
#pragma unroll
            for (int kk = 0; kk < 2; ++kk) {
                bf8_t af = *(const bf8_t*)(&As[ln * GLD + kk * 32 + quad * 8]);
#pragma unroll
                for (int n = 0; n < 3; ++n) {
                    int fn = wave + n * 4;
                    bf8_t bfr = *(const bf8_t*)(&Bs[(fn * 16 + ln) * GLD + kk * 32 + quad * 8]);
                    acch[n] = __builtin_amdgcn_mfma_f32_16x16x32_bf16(af, bfr, acch[n], 0, 0, 0);
                }
            }
        }
    }

    // GRU epilogue: acc=ir/iz/in + bih; acch=hr/hz/hn + bhh. Register-local.
    {
        const int col = cg * 64 + wave * 16 + ln;
        float bi_r = w[F_BIH + col];
        float bi_z = w[F_BIH + 256 + col];
        float bi_n = w[F_BIH + 512 + col];
        float bh_r = w[F_BCAT + 512 + col];
        float bh_z = w[F_BCAT + 768 + col];
        float bh_n = w[F_BCAT + 1024 + col];
#pragma unroll
        for (int r = 0; r < 4; ++r) {
            int row = rbase + quad * 4 + r;
            float ir = acc[0][r] + bi_r;
            float iz = acc[1][r] + bi_z;
            float in = acc[2][r] + bi_n;
            float hr = acch[0][r] + bh_r;
            float hz = acch[1][r] + bh_z;
            float hn = acch[2][r] + bh_n;
            float rg_ = 1.f / (1.f + __expf(-(ir + hr)));
            float z   = 1.f / (1.f + __expf(-(iz + hz)));
            float nn  = tanhf(in + rg_ * hn);
            float ho = w[F_H + row * 256 + col];
            float hv = (1.f - z) * nn + z * ho;
            w[F_H + row * 256 + col] = hv;
            if (!FINAL) {
                ushort_t hb = f2b(hv);
                wb[UB_H2 + row * 512 + col] = hb;
                wb[UB_H2 + row * 512 + 256 + col] = f2b(hv - bf2f(hb));
            }
        }
    }

    if (FINAL) {
        // per-graph arrival counter: 64 blocks/graph; last one does readout.
        const int g = rg >> 4;
        __syncthreads();
        if (t == 0) {
            __threadfence();                           // release h writes
            int prev = atomicAdd((int*)(w + F_GCNT) + g, 1);
            donef = (prev == 63);
        }
        __syncthreads();
        if (!donef) return;
        __threadfence();                               // acquire others' h

        const float* hb = w + F_H + g * 256 * 256;
        float s = 0.f;
        for (int n = 0; n < 256; ++n) s += hb[n * 256 + t];
        gl[t] = s;
        __syncthreads();
        float acc1 = w[F_ROB1 + t];
        for (int k = 0; k < 256; ++k) acc1 += gl[k] * w[F_ROW1 + k * 256 + t];
        t1[t] = relu(acc1);
        __syncthreads();
        if (t < 16) {
            float q = w[F_ROB2 + t];
            for (int k = 0; k < 256; ++k) q += t1[k] * w[F_ROW2 + k * 16 + t];
            if (*(const int*)(w + F_FLAG)) ((float*)out)[g * 16 + t] = q;
            else ((__hip_bfloat16*)out)[g * 16 + t] = __float2bfloat16(q);
        }
    }
}

extern "C" void kernel_launch(void* const* d_in, const int* in_sizes, int n_in,
                              void* d_out, int out_size, void* d_ws, size_t ws_size,
                              hipStream_t stream) {
    float* w = (float*)d_ws;
    ushort_t* wb = (ushort_t*)d_ws;

    static const int dictSz[18]  = {65536,262144,16384,256,65536,256,131072,256,65536,256,
                                    196608,196608,768,768,65536,256,4096,16};
    static const int alphaSz[18] = {262144,196608,196608,768,768,131072,65536,256,256,
                                    65536,16384,65536,256,256,65536,4096,256,16};
    static const int alphaPos[18] = {9,0,10,12,11,13,5,7,6,8,2,1,4,3,14,16,15,17};
    bool dictOK = true, alphaOK = true;
    for (int i = 0; i < 18 && i < n_in; ++i) {
        if (in_sizes[i] != dictSz[i])  dictOK = false;
        if (in_sizes[i] != alphaSz[i]) alphaOK = false;
    }
    const void* P[18];
    for (int l = 0; l < 18; ++l) P[l] = d_in[(!dictOK && alphaOK) ? alphaPos[l] : l];
    const int* adj = (const int*)P[1];

    convwg_kernel<<<NCONV + 216, 256, 0, stream>>>(
        P[0], P[2], P[3], P[4], P[5], P[6], P[7], P[8], P[9],
        P[10], P[11], P[12], P[13], P[14], P[15], P[16], P[17], w);

    prenet_kernel<<<32, 256, 0, stream>>>(w);

    for (int it = 0; it < 3; ++it) {
        hcat_kernel<<<128, 256, 0, stream>>>(w);
        msg_kernel<<<BN_ROWS, 256, 0, stream>>>(w + F_HCAT, adj, wb + UB_EHAT2);
        if (it < 2)
            gigru_kernel<0><<<256, 256, 0, stream>>>(w, d_out);
        else
            gigru_kernel<1><<<256, 256, 0, stream>>>(w, d_out);
    }
}

// Round 11
// 257.646 us; speedup vs baseline: 1.3685x; 1.0197x over previous
//
#include <hip/hip_runtime.h>
#include <hip/hip_bf16.h>

// B=4, N=256, F=64, H=256, A=16, T=3.  BN=1024 rows.
// bf16 inputs (runtime-verified); adjacency int32.
// GEMMs: bf16 MFMA 16x16x32. Weights are EXACT in bf16 (inputs are bf16).
// Precision: activations h/Ehat stored as split hi/lo bf16 pairs along K,
// weights duplicated along K -> A_hi@B + A_lo@B in one MFMA GEMM (~fp32 acc).
// R1-R8: fusion + K-dedup + LDS pad: 297us. R9: 256-blk gigru: 265us.
// R10: gh-fusion: 262.7us. gigru 47.6us INVARIANT to k-rounds/blocks/epilogue.
//     FETCH stuck at 7.2MB for a 3.5MB working set -> nearly every staged
//     load is a cross-XCD RAW (producer kernel's blocks on other XCDs);
//     dirty-line service via L3/HBM at ~900cy dominates.
// R11: graph<->XCD affinity. All work for graph g (prenet/hcat/msg/gigru/
//     readout) pinned to XCDs {2g,2g+1} via bid = j*8 + 2g + parity decode.
//     Producer and consumer share an L2 -> RAW becomes ~200cy L2 hit.
//     Pure blockIdx remap; numerics bitwise identical.

typedef unsigned short ushort_t;
typedef short bf8_t __attribute__((ext_vector_type(8)));
typedef float f4_t  __attribute__((ext_vector_type(4)));

#define BN_ROWS 1024

// ---- bf16 regions (USHORT offsets) ----
#define UB_NFB    0         // 65536   NF [1024][64] (exact)
#define UB_PW1T   65536     // 16384   preW1^T [256][64]
#define UB_PW2T   81920     // 65536   preW2^T [256][256]
#define UB_WCATT  147456    // 327680  Wcat^T [1280][256] (dedup: k&255)
#define UB_WGT    475136    // 442368  Wg^T [768][576] = [hi(288)|lo(288)]
#define UB_H2     917504    // 524288  h  [1024][512] hi|lo
#define UB_EHAT2  1441792   // 589824  Ehat [1024][576] = [Eh(288)|El(288)]
// end 2031616 ushorts = 1015808 floats

// ---- fp32 regions (FLOAT offsets) ----
#define F_PREB1   1015808   // 256
#define F_PREB2   1016064   // 256
#define F_BCAT    1016320   // 1280  [msg_b1 | 0 | gru_bhh]
#define F_BIH     1017600   // 768
#define F_ROW1    1018368   // 65536
#define F_ROB1    1083904   // 256
#define F_ROW2    1084160   // 4096
#define F_ROB2    1088256   // 16
#define F_H       1088272   // 262144
#define F_HCAT    1350416   // 524288 [hi_p | hj]
#define F_FLAG    2661136   // 1 int
#define F_GCNT    2661140   // 4 ints: per-graph readout arrival counters

// ---- convert index space ----
#define CVa 65536     // end NFB
#define CVb 81920     // end PW1T
#define CVc 147456    // end PW2T
#define CVd 475136    // end WCATT (1280*256)
#define CV_TOTAL 547600   // + 72464 fp32 tail
#define NCONV 1070        // convert blocks (2 elems/thread); wg blocks follow

__device__ __forceinline__ float bf2f(ushort_t u) {
    return __uint_as_float(((unsigned int)u) << 16);
}
__device__ __forceinline__ ushort_t f2b(float v) {
    __hip_bfloat16 b = __float2bfloat16(v);
    return *reinterpret_cast<ushort_t*>(&b);
}
__device__ __forceinline__ float relu(float v) { return v < 0.f ? 0.f : v; }  // NaN-propagating
__device__ __forceinline__ float ld(const void* p, int i, int isf32) {
    return isf32 ? ((const float*)p)[i] : bf2f(((const ushort_t*)p)[i]);
}

// detect + convert (blocks [0,NCONV)) + wg (blocks [NCONV,NCONV+216)).
__global__ __launch_bounds__(256) void convwg_kernel(
    const void* nf, const void* preW1, const void* preb1, const void* preW2, const void* preb2,
    const void* msgW1, const void* msgb1, const void* msgW2, const void* msgb2,
    const void* gruWih, const void* gruWhh, const void* grubih, const void* grubhh,
    const void* roW1, const void* rob1, const void* roW2, const void* rob2,
    float* __restrict__ w)
{
    __shared__ float w2s[4 * 256];
    __shared__ int cnt;
    const int t = threadIdx.x;
    ushort_t* wb = (ushort_t*)w;

    // ---- inline detect (redundant per block; 4KB L2-hit scan) ----
    if (t == 0) cnt = 0;
    __syncthreads();
    {
        const ushort_t* nf0 = (const ushort_t*)nf;
        int bad = 0;
        for (int i = 0; i < 8; ++i) {
            ushort_t u = nf0[(t * 8 + i) * 2];
            int ex = (u >> 7) & 0xFF;
            if ((u & 0x7fff) != 0 && (ex < 100 || ex > 140)) bad++;
        }
        atomicAdd(&cnt, bad);
    }
    __syncthreads();
    const int f32 = (cnt > 512) ? 1 : 0;

    if (blockIdx.x == 0) {          // publish flag + zero readout counters
        if (t < 4) ((int*)(w + F_GCNT))[t] = 0;
        if (t == 4) *(int*)(w + F_FLAG) = f32;
    }

    if (blockIdx.x < NCONV) {
        const int e0 = (blockIdx.x * 256 + t) * 2;
#pragma unroll
        for (int u2 = 0; u2 < 2; ++u2) {
            int e = e0 + u2;
            if (e >= CV_TOTAL) break;
            if (e < CVa) {                                    // NF
                wb[UB_NFB + e] = f2b(ld(nf, e, f32));
            } else if (e < CVb) {                             // preW1^T [256][64]
                int i = e - CVa; int n = i >> 6, k = i & 63;
                wb[UB_PW1T + i] = f2b(ld(preW1, k * 256 + n, f32));
            } else if (e < CVc) {                             // preW2^T [256][256]
                int i = e - CVb; int n = i >> 8, k = i & 255;
                wb[UB_PW2T + i] = f2b(ld(preW2, k * 256 + n, f32));
            } else if (e < CVd) {                             // Wcat^T [1280][256]
                int i = e - CVc; int n = i >> 8, k = i & 255;
                float v;
                if (n < 256)      v = ld(msgW1, k * 256 + n, f32);
                else if (n < 512) v = ld(msgW1, (256 + k) * 256 + (n - 256), f32);
                else              v = ld(gruWhh, k * 768 + (n - 512), f32);
                wb[UB_WCATT + i] = f2b(v);
            } else {                                          // fp32 tail
                int f = e - CVd;
                float v;
                if (f < 256)        v = ld(preb1, f, f32);
                else if (f < 512)   v = ld(preb2, f - 256, f32);
                else if (f < 1792) {
                    int c = f - 512;
                    if (c < 256)      v = ld(msgb1, c, f32);
                    else if (c < 512) v = 0.f;
                    else              v = ld(grubhh, c - 512, f32);
                }
                else if (f < 2560)  v = ld(grubih, f - 1792, f32);
                else if (f < 68096) v = ld(roW1, f - 2560, f32);
                else if (f < 68352) v = ld(rob1, f - 68096, f32);
                else if (f < 72448) v = ld(roW2, f - 68352, f32);
                else                v = ld(rob2, f - 72448, f32);
                w[F_PREB1 + f] = v;
            }
        }
        return;
    }

    // ---- wg path: Wg[k][p] = sum_n W2hat[k][n]*Wih[n][p] -> WgT[p][576] ----
    const int wt = blockIdx.x - NCONV;   // [0,216)
    const int p0 = (wt % 3) * 256;
    const int k0 = (wt / 3) * 4;
    for (int i = t; i < 4 * 256; i += 256) {
        int r = i >> 8, n = i & 255;
        int krow = k0 + r;
        float v;
        if (krow < 256)       v = ld(msgW2, krow * 256 + n, f32);
        else if (krow == 256) v = ld(msgb2, n, f32);
        else                  v = 0.f;
        w2s[i] = v;
    }
    __syncthreads();
    const int p = p0 + t;
    float acc4[4] = {};
    for (int n0 = 0; n0 < 256; n0 += 32) {
        float wv[32];
#pragma unroll
        for (int i = 0; i < 32; ++i)
            wv[i] = ld(gruWih, (n0 + i) * 768 + p, f32);
#pragma unroll
        for (int r = 0; r < 4; ++r) {
            float acc = acc4[r];
#pragma unroll
            for (int q = 0; q < 8; ++q) {
                f4_t w4 = *(const f4_t*)&w2s[r * 256 + n0 + q * 4];
                acc += w4[0] * wv[q * 4 + 0] + w4[1] * wv[q * 4 + 1]
                     + w4[2] * wv[q * 4 + 2] + w4[3] * wv[q * 4 + 3];
            }
            acc4[r] = acc;
        }
    }
#pragma unroll
    for (int r = 0; r < 4; ++r) {
        int krow = k0 + r;
        ushort_t hi = f2b(acc4[r]);
        ushort_t lo = f2b(acc4[r] - bf2f(hi));
        wb[UB_WGT + p * 576 + krow] = hi;
        wb[UB_WGT + p * 576 + 288 + krow] = lo;
    }
}

// Fused pre-net: X = relu(NF@preW1+b1) (in LDS), h = X@preW2+b2.
// 32 blocks x 32 rows, XCD-pinned: graph g on XCDs {2g,2g+1}.
__global__ __launch_bounds__(256) void prenet_kernel(float* __restrict__ w)
{
    __shared__ ushort_t As[32 * 64];    // NF tile      4KB
    __shared__ ushort_t Xs[32 * 256];   // X tile      16KB
    __shared__ ushort_t Bs[256 * 32];   // weight slab 16KB
    ushort_t* wb = (ushort_t*)w;
    const int t = threadIdx.x;
    const int wave = t >> 6, lane = t & 63;
    const int ln = lane & 15, quad = lane >> 4;
    const int wr = (wave & 1) * 16, wc = (wave >> 1) * 128;
    const int xcd = blockIdx.x & 7;
    const int gph = xcd >> 1;
    const int lidx = ((blockIdx.x >> 3) << 1) | (xcd & 1);   // 0..7
    const int rbase = gph * 256 + lidx * 32;
    const int srow = t >> 2, skc = (t & 3) << 3;

    // stage NF tile [32][64]: 1 bf8 per thread
    {
        int row = t >> 3, kc = (t & 7) << 3;
        *(bf8_t*)(&As[row * 64 + kc]) =
            *(const bf8_t*)(&wb[UB_NFB + (rbase + row) * 64 + kc]);
    }

    f4_t acc[8] = {};
    // phase A: X = relu(NF @ PW1T + b1), K=64
    for (int k0 = 0; k0 < 64; k0 += 32) {
        __syncthreads();
#pragma unroll
        for (int rr = 0; rr < 4; ++rr) {
            int n = srow + 64 * rr;
            *(bf8_t*)(&Bs[n * 32 + skc]) =
                *(const bf8_t*)(&wb[UB_PW1T + n * 64 + k0 + skc]);
        }
        __syncthreads();
        bf8_t af = *(const bf8_t*)(&As[(wr + ln) * 64 + k0 + quad * 8]);
#pragma unroll
        for (int n = 0; n < 8; ++n) {
            bf8_t bfr = *(const bf8_t*)(&Bs[(wc + n * 16 + ln) * 32 + quad * 8]);
            acc[n] = __builtin_amdgcn_mfma_f32_16x16x32_bf16(af, bfr, acc[n], 0, 0, 0);
        }
    }
    __syncthreads();
#pragma unroll
    for (int n = 0; n < 8; ++n) {
        int col = wc + n * 16 + ln;
        float bb = w[F_PREB1 + col];
#pragma unroll
        for (int r = 0; r < 4; ++r) {
            int row = wr + quad * 4 + r;
            Xs[row * 256 + col] = f2b(relu(acc[n][r] + bb));
        }
        acc[n] = (f4_t){0.f, 0.f, 0.f, 0.f};
    }
    __syncthreads();

    // phase B: h = X @ PW2T + b2, K=256
    for (int k0 = 0; k0 < 256; k0 += 32) {
        __syncthreads();
#pragma unroll
        for (int rr = 0; rr < 4; ++rr) {
            int n = srow + 64 * rr;
            *(bf8_t*)(&Bs[n * 32 + skc]) =
                *(const bf8_t*)(&wb[UB_PW2T + n * 256 + k0 + skc]);
        }
        __syncthreads();
        bf8_t af = *(const bf8_t*)(&Xs[(wr + ln) * 256 + k0 + quad * 8]);
#pragma unroll
        for (int n = 0; n < 8; ++n) {
            bf8_t bfr = *(const bf8_t*)(&Bs[(wc + n * 16 + ln) * 32 + quad * 8]);
            acc[n] = __builtin_amdgcn_mfma_f32_16x16x32_bf16(af, bfr, acc[n], 0, 0, 0);
        }
    }
#pragma unroll
    for (int n = 0; n < 8; ++n) {
        int col = wc + n * 16 + ln;
        float bb = w[F_PREB2 + col];
#pragma unroll
        for (int r = 0; r < 4; ++r) {
            int grow = rbase + wr + quad * 4 + r;
            float v = acc[n][r] + bb;
            w[F_H + grow * 256 + col] = v;
            ushort_t hi = f2b(v);
            wb[UB_H2 + grow * 512 + col] = hi;
            wb[UB_H2 + grow * 512 + 256 + col] = f2b(v - bf2f(hi));
        }
    }
}

// hcat GEMM: C[1024,512] = H2[1024,512] @ WcatT[0..512]^T + bias ([hi_p|hj]).
// 32x128 tiles, 128 blocks, XCD-pinned: graph g = bm/256 on XCDs {2g,2g+1}.
// BK=64 (8 rounds), LDS stride 104u, reg-prefetch distance 1.
#define HLD 104
__global__ __launch_bounds__(256) void hcat_kernel(float* __restrict__ w)
{
    __shared__ ushort_t As[32 * HLD];    // 6.6KB
    __shared__ ushort_t Bs[128 * HLD];   // 26.6KB
    ushort_t* wb = (ushort_t*)w;
    const ushort_t* A  = wb + UB_H2;
    const ushort_t* Bt = wb + UB_WCATT;
    const int t = threadIdx.x;
    const int wave = t >> 6, lane = t & 63;
    const int ln = lane & 15, quad = lane >> 4;
    const int xcd = blockIdx.x & 7;
    const int gph = xcd >> 1;
    const int lidx = ((blockIdx.x >> 3) << 1) | (xcd & 1);   // 0..31
    const int bm = gph * 256 + (lidx >> 2) * 32;
    const int bn = (lidx & 3) * 128;
    const int wm = (wave >> 1) * 16, wn = (wave & 1) * 64;

    // staging: A 32 rows x 64u = 256 chunks (1/thread); B 128x64u (4/thread)
    const int arow = t >> 3, akc = (t & 7) << 3;
    const int agoff = (bm + arow) * 512 + akc;
    const int aloff = arow * HLD + akc;
    int bgoff[4], bloff[4];
#pragma unroll
    for (int i = 0; i < 4; ++i) {
        int slot = i * 256 + t;
        int brow = slot >> 3, bkc = (slot & 7) << 3;
        bgoff[i] = (bn + brow) * 256 + bkc;
        bloff[i] = brow * HLD + bkc;
    }

    f4_t acc[4] = {};
    bf8_t ra, rb[4];

    ra = *(const bf8_t*)(&A[agoff]);
#pragma unroll
    for (int i = 0; i < 4; ++i)
        rb[i] = *(const bf8_t*)(&Bt[bgoff[i]]);

    for (int ks = 0; ks < 8; ++ks) {
        __syncthreads();
        *(bf8_t*)(&As[aloff]) = ra;
#pragma unroll
        for (int i = 0; i < 4; ++i)
            *(bf8_t*)(&Bs[bloff[i]]) = rb[i];
        __syncthreads();
        if (ks < 7) {
            int k0 = (ks + 1) * 64;
            int kb = k0 & 255;
            ra = *(const bf8_t*)(&A[agoff + k0]);
#pragma unroll
            for (int i = 0; i < 4; ++i)
                rb[i] = *(const bf8_t*)(&Bt[bgoff[i] + kb]);
        }
#pragma unroll
        for (int kk = 0; kk < 2; ++kk) {
            bf8_t af = *(const bf8_t*)(&As[(wm + ln) * HLD + kk * 32 + quad * 8]);
#pragma unroll
            for (int ni = 0; ni < 4; ++ni) {
                bf8_t bfr = *(const bf8_t*)(&Bs[(wn + ni * 16 + ln) * HLD + kk * 32 + quad * 8]);
                acc[ni] = __builtin_amdgcn_mfma_f32_16x16x32_bf16(af, bfr, acc[ni], 0, 0, 0);
            }
        }
    }

#pragma unroll
    for (int ni = 0; ni < 4; ++ni) {
        int col = bn + wn + ni * 16 + ln;
        float bb = w[F_BCAT + col];
#pragma unroll
        for (int r = 0; r < 4; ++r) {
            int row = bm + wm + quad * 4 + r;
            w[F_HCAT + row * 512 + col] = acc[ni][r] + bb;
        }
    }
}

// Ehat[row] (width 576): [ sum relu(hi_p+hj) hi (256) | deg | 0 | lo (256) | 0 ]
// 1024 blocks, XCD-pinned: row's graph on XCDs {2g,2g+1}.
__global__ __launch_bounds__(256) void msg_kernel(
    const float* __restrict__ hcat,   // [1024][512]: [hi_p | hj]
    const int*   __restrict__ adj,    // [1024][256]
    ushort_t* __restrict__ ehat)      // [1024][576]
{
    const int xcd = blockIdx.x & 7;
    const int gph = xcd >> 1;
    const int idx = ((blockIdx.x >> 3) << 1) | (xcd & 1);  // 0..255
    const int row = gph * 256 + idx;
    const int t = threadIdx.x;
    __shared__ int ej[256];
    __shared__ int ecnt;
    if (t == 0) ecnt = 0;
    __syncthreads();
    if (adj[row * 256 + t]) { int p = atomicAdd(&ecnt, 1); ej[p] = t; }
    const float hi = hcat[row * 512 + t];
    const float* hjb = hcat + gph * 256 * 512 + 256;
    __syncthreads();
    const int ne = ecnt;
    float acc = 0.f;
#pragma unroll 4
    for (int p = 0; p < ne; ++p) {
        int j = ej[p];
        acc += relu(hi + hjb[j * 512 + t]);
    }
    ushort_t h16 = f2b(acc);
    ushort_t l16 = f2b(acc - bf2f(h16));
    ushort_t* er = ehat + row * 576;
    er[t] = h16;
    er[288 + t] = l16;
    if (t < 32) {
        er[256 + t] = f2b(t == 0 ? (float)ne : 0.f);  // deg exact (<=256)
        er[544 + t] = 0;
    }
}

// Fused gi-GEMM + gh-GEMM + GRU.  256 blocks, XCD-pinned:
//   xcd=bid&7; gph=xcd>>1; l=((bid>>3)<<1)|(xcd&1) (0..63); cg=l&3;
//   rg=gph*16+(l>>2) -> all of graph g's panels on XCDs {2g,2g+1}.
// Phase 1: gi = Ehat @ Wg (logical K=864 via dedup remap), BK=96, 9 rounds.
// Phase 2: gh = h @ Whh (K=512, B=WCATT rows 512..1280 dedup k&255), BK=64.
// GRU epilogue register-local. FINAL: last block per graph does readout.
#define GLD 104
template<int FINAL>
__global__ __launch_bounds__(256) void gigru_kernel(float* __restrict__ w,
                                                    void* __restrict__ out)
{
    __shared__ ushort_t As[16 * GLD];    // 3.3KB
    __shared__ ushort_t Bs[192 * GLD];   // 40KB
    __shared__ float gl[256];
    __shared__ float t1[256];
    __shared__ int donef;
    ushort_t* wb = (ushort_t*)w;
    const int t = threadIdx.x;
    const int wave = t >> 6, lane = t & 63;
    const int ln = lane & 15, quad = lane >> 4;
    const int xcd = blockIdx.x & 7;
    const int gph = xcd >> 1;
    const int lidx = ((blockIdx.x >> 3) << 1) | (xcd & 1);   // 0..63
    const int cg = lidx & 3;
    const int rg = gph * 16 + (lidx >> 2);                   // 0..63
    const int rbase = rg * 16;

    // ---------------- phase 1: gi = Ehat @ Wg ----------------
    const int aval = (t < 192);
    const int arow = t / 12, akc = (t % 12) * 8;
    const int agoff = (rbase + arow) * 576 + akc;
    const int aloff = arow * GLD + akc;
    int bgoff[9], bloff[9];
#pragma unroll
    for (int i = 0; i < 9; ++i) {
        int slot = i * 256 + t;
        int brow = slot / 12, bkc = (slot % 12) * 8;
        int wrow = (brow >> 6) * 256 + cg * 64 + (brow & 63);
        bgoff[i] = wrow * 576 + bkc;
        bloff[i] = brow * GLD + bkc;
    }
    const ushort_t* Ehp = wb + UB_EHAT2;
    const ushort_t* Bp  = wb + UB_WGT;

    f4_t acc[3] = {};
    {
        bf8_t ra, rb[9];
        if (aval) ra = *(const bf8_t*)(&Ehp[agoff]);
#pragma unroll
        for (int i = 0; i < 9; ++i)
            rb[i] = *(const bf8_t*)(&Bp[bgoff[i]]);

        for (int ks = 0; ks < 9; ++ks) {
            __syncthreads();
            if (aval) *(bf8_t*)(&As[aloff]) = ra;
#pragma unroll
            for (int i = 0; i < 9; ++i)
                *(bf8_t*)(&Bs[bloff[i]]) = rb[i];
            __syncthreads();
            if (ks < 8) {
                int k0 = (ks + 1) * 96;
                int ka = (k0 < 576) ? k0 : k0 - 576;
                int kb = (k0 < 288) ? k0 : k0 - 288;
                if (aval) ra = *(const bf8_t*)(&Ehp[agoff + ka]);
#pragma unroll
                for (int i = 0; i < 9; ++i)
                    rb[i] = *(const bf8_t*)(&Bp[bgoff[i] + kb]);
            }
#pragma unroll
            for (int kk = 0; kk < 3; ++kk) {
                bf8_t af = *(const bf8_t*)(&As[ln * GLD + kk * 32 + quad * 8]);
#pragma unroll
                for (int n = 0; n < 3; ++n) {
                    int fn = wave + n * 4;           // gate n, sub = wave
                    bf8_t bfr = *(const bf8_t*)(&Bs[(fn * 16 + ln) * GLD + kk * 32 + quad * 8]);
                    acc[n] = __builtin_amdgcn_mfma_f32_16x16x32_bf16(af, bfr, acc[n], 0, 0, 0);
                }
            }
        }
    }

    // ---------------- phase 2: gh = h @ Whh ----------------
    // A = H2 [16][512]; B = WCATT rows 512 + gate*256 + cg*64 + r (dedup k&255)
    const int aval2 = (t < 128);
    const int arow2 = t >> 3, akc2 = (t & 7) << 3;
    const int agoff2 = (rbase + arow2) * 512 + akc2;
    const int aloff2 = arow2 * GLD + akc2;
    int bgoff2[6], bloff2[6];
#pragma unroll
    for (int i = 0; i < 6; ++i) {
        int slot = i * 256 + t;
        int brow = slot >> 3, bkc = (slot & 7) << 3;
        int wrow = 512 + (brow >> 6) * 256 + cg * 64 + (brow & 63);
        bgoff2[i] = wrow * 256 + bkc;
        bloff2[i] = brow * GLD + bkc;
    }
    const ushort_t* Hp = wb + UB_H2;
    const ushort_t* Wp = wb + UB_WCATT;

    f4_t acch[3] = {};
    {
        bf8_t ra, rb[6];
        if (aval2) ra = *(const bf8_t*)(&Hp[agoff2]);
#pragma unroll
        for (int i = 0; i < 6; ++i)
            rb[i] = *(const bf8_t*)(&Wp[bgoff2[i]]);

        for (int ks = 0; ks < 8; ++ks) {
            __syncthreads();
            if (aval2) *(bf8_t*)(&As[aloff2]) = ra;
#pragma unroll
            for (int i = 0; i < 6; ++i)
                *(bf8_t*)(&Bs[bloff2[i]]) = rb[i];
            __syncthreads();
            if (ks < 7) {
                int k0 = (ks + 1) * 64;
                int kb = k0 & 255;
                if (aval2) ra = *(const bf8_t*)(&Hp[agoff2 + k0]);
#pragma unroll
                for (int i = 0; i < 6; ++i)
                    rb[i] = *(const bf8_t*)(&Wp[bgoff2[i] + kb]);
            }
#pragma unroll
            for (int kk = 0; kk < 2; ++kk) {
                bf8_t af = *(const bf8_t*)(&As[ln * GLD + kk * 32 + quad * 8]);
#pragma unroll
                for (int n = 0; n < 3; ++n) {
                    int fn = wave + n * 4;
                    bf8_t bfr = *(const bf8_t*)(&Bs[(fn * 16 + ln) * GLD + kk * 32 + quad * 8]);
                    acch[n] = __builtin_amdgcn_mfma_f32_16x16x32_bf16(af, bfr, acch[n], 0, 0, 0);
                }
            }
        }
    }

    // GRU epilogue: acc=ir/iz/in + bih; acch=hr/hz/hn + bhh. Register-local.
    {
        const int col = cg * 64 + wave * 16 + ln;
        float bi_r = w[F_BIH + col];
        float bi_z = w[F_BIH + 256 + col];
        float bi_n = w[F_BIH + 512 + col];
        float bh_r = w[F_BCAT + 512 + col];
        float bh_z = w[F_BCAT + 768 + col];
        float bh_n = w[F_BCAT + 1024 + col];
#pragma unroll
        for (int r = 0; r < 4; ++r) {
            int row = rbase + quad * 4 + r;
            float ir = acc[0][r] + bi_r;
            float iz = acc[1][r] + bi_z;
            float in = acc[2][r] + bi_n;
            float hr = acch[0][r] + bh_r;
            float hz = acch[1][r] + bh_z;
            float hn = acch[2][r] + bh_n;
            float rg_ = 1.f / (1.f + __expf(-(ir + hr)));
            float z   = 1.f / (1.f + __expf(-(iz + hz)));
            float nn  = tanhf(in + rg_ * hn);
            float ho = w[F_H + row * 256 + col];
            float hv = (1.f - z) * nn + z * ho;
            w[F_H + row * 256 + col] = hv;
            if (!FINAL) {
                ushort_t hb = f2b(hv);
                wb[UB_H2 + row * 512 + col] = hb;
                wb[UB_H2 + row * 512 + 256 + col] = f2b(hv - bf2f(hb));
            }
        }
    }

    if (FINAL) {
        // per-graph arrival counter: 64 blocks/graph; last one does readout.
        const int g = gph;
        __syncthreads();
        if (t == 0) {
            __threadfence();                           // release h writes
            int prev = atomicAdd((int*)(w + F_GCNT) + g, 1);
            donef = (prev == 63);
        }
        __syncthreads();
        if (!donef) return;
        __threadfence();                               // acquire others' h

        const float* hb = w + F_H + g * 256 * 256;
        float s = 0.f;
        for (int n = 0; n < 256; ++n) s += hb[n * 256 + t];
        gl[t] = s;
        __syncthreads();
        float acc1 = w[F_ROB1 + t];
        for (int k = 0; k < 256; ++k) acc1 += gl[k] * w[F_ROW1 + k * 256 + t];
        t1[t] = relu(acc1);
        __syncthreads();
        if (t < 16) {
            float q = w[F_ROB2 + t];
            for (int k = 0; k < 256; ++k) q += t1[k] * w[F_ROW2 + k * 16 + t];
            if (*(const int*)(w + F_FLAG)) ((float*)out)[g * 16 + t] = q;
            else ((__hip_bfloat16*)out)[g * 16 + t] = __float2bfloat16(q);
        }
    }
}

extern "C" void kernel_launch(void* const* d_in, const int* in_sizes, int n_in,
                              void* d_out, int out_size, void* d_ws, size_t ws_size,
                              hipStream_t stream) {
    float* w = (float*)d_ws;
    ushort_t* wb = (ushort_t*)d_ws;

    static const int dictSz[18]  = {65536,262144,16384,256,65536,256,131072,256,65536,256,
                                    196608,196608,768,768,65536,256,4096,16};
    static const int alphaSz[18] = {262144,196608,196608,768,768,131072,65536,256,256,
                                    65536,16384,65536,256,256,65536,4096,256,16};
    static const int alphaPos[18] = {9,0,10,12,11,13,5,7,6,8,2,1,4,3,14,16,15,17};
    bool dictOK = true, alphaOK = true;
    for (int i = 0; i < 18 && i < n_in; ++i) {
        if (in_sizes[i] != dictSz[i])  dictOK = false;
        if (in_sizes[i] != alphaSz[i]) alphaOK = false;
    }
    const void* P[18];
    for (int l = 0; l < 18; ++l) P[l] = d_in[(!dictOK && alphaOK) ? alphaPos[l] : l];
    const int* adj = (const int*)P[1];

    convwg_kernel<<<NCONV + 216, 256, 0, stream>>>(
        P[0], P[2], P[3], P[4], P[5], P[6], P[7], P[8], P[9],
        P[10], P[11], P[12], P[13], P[14], P[15], P[16], P[17], w);

    prenet_kernel<<<32, 256, 0, stream>>>(w);

    for (int it = 0; it < 3; ++it) {
        hcat_kernel<<<128, 256, 0, stream>>>(w);
        msg_kernel<<<BN_ROWS, 256, 0, stream>>>(w + F_HCAT, adj, wb + UB_EHAT2);
        if (it < 2)
            gigru_kernel<0><<<256, 256, 0, stream>>>(w, d_out);
        else
            gigru_kernel<1><<<256, 256, 0, stream>>>(w, d_out);
    }
}